// Round 5
// baseline (1318.679 us; speedup 1.0000x reference)
//
#include <hip/hip_runtime.h>

#define N_NODES 50000
#define N_EDGES 800000
#define NGRAPH  128
#define XPITCH  72   // ushort pitch for 64-wide LDS activation rows (16B-aligned, 2-way banks)
#define NB      391  // dst buckets of 128 nodes
#define HEPB    4096 // edges per block, histogram kernel
#define SEPB    8192 // edges per block, scatter kernel

typedef short bf16x8 __attribute__((ext_vector_type(8)));
typedef float f32x4  __attribute__((ext_vector_type(4)));

// ---------------------------------------------------------------------------
// helpers
// ---------------------------------------------------------------------------

__device__ __forceinline__ float atomAddF(float* p, float v) {
#if defined(__gfx950__) || defined(__AMDGCN__)
    return unsafeAtomicAdd(p, v);
#else
    return atomicAdd(p, v);
#endif
}

__device__ __forceinline__ unsigned short f2bf(float x) {  // RNE f32 -> bf16
    unsigned u = __builtin_bit_cast(unsigned, x);
    u += 0x7fffu + ((u >> 16) & 1u);
    return (unsigned short)(u >> 16);
}
__device__ __forceinline__ float bf2f(unsigned short h) {
    return __builtin_bit_cast(float, (unsigned)h << 16);
}

// One 16x16 C-tile: acc += X[16mt..+16][K] @ WT^T[16nt..+16] over NKC k-chunks.
template<int NKC, int KROW>
__device__ __forceinline__ f32x4 tile_mm(const unsigned short* __restrict__ Xlds,
                                         const unsigned short* __restrict__ WT,
                                         int mt, int nt, int lane, f32x4 acc) {
    int col  = lane & 15;
    int quad = lane >> 4;
    const unsigned short* xp = Xlds + (mt * 16 + col) * XPITCH + quad * 8;
    const unsigned short* wp = WT + (nt * 16 + col) * KROW + quad * 8;
#pragma unroll
    for (int c = 0; c < NKC; ++c) {
        bf16x8 a = *(const bf16x8*)(xp + c * 32);
        bf16x8 b = *(const bf16x8*)(wp + c * 32);
        acc = __builtin_amdgcn_mfma_f32_16x16x32_bf16(a, b, acc, 0, 0, 0);
    }
    return acc;
}

__device__ __forceinline__ f32x4 mk4(float b) { f32x4 a = {b, b, b, b}; return a; }

// C/D layout: col=lane&15 (=n offset), row=quad*4+reg (=m offset)
__device__ __forceinline__ void ep_lds(unsigned short* __restrict__ Xo, int wv, int nt,
                                       int lane, f32x4 acc, bool relu) {
    int col = lane & 15, quad = lane >> 4;
#pragma unroll
    for (int r = 0; r < 4; ++r) {
        float xv = acc[r];
        if (relu) xv = fmaxf(xv, 0.f);
        Xo[(wv * 16 + quad * 4 + r) * XPITCH + nt * 16 + col] = f2bf(xv);
    }
}

__device__ __forceinline__ void ep_glob(unsigned short* __restrict__ g, int nodeBase,
                                        int nvalid, int wv, int nt, int lane, f32x4 acc) {
    int col = lane & 15, quad = lane >> 4;
#pragma unroll
    for (int r = 0; r < 4; ++r) {
        int nl = wv * 16 + quad * 4 + r;
        if (nl < nvalid)
            g[(size_t)(nodeBase + nl) * 64 + nt * 16 + col] = f2bf(acc[r]);
    }
}

// ---------------------------------------------------------------------------
// weight prep (transpose + bf16 into B-operand layout)
// ---------------------------------------------------------------------------
#define OFF_NW1T  0
#define OFF_NW2T  2048
#define OFF_LYR   6144
#define LYR_SZ    20480
#define OFF_LIN1T 67584
#define OFF_LIN2T 69632
#define WT_TOTAL  70144

__global__ __launch_bounds__(256) void kPrep(
    const float* __restrict__ nW1, const float* __restrict__ nW2,
    const float* __restrict__ lW1, const float* __restrict__ lW2,
    const float* __restrict__ gW1, const float* __restrict__ gW2,
    const float* __restrict__ lin1W, const float* __restrict__ lin2W,
    unsigned short* __restrict__ WT) {
    int i = blockIdx.x * 256 + threadIdx.x;
    if (i >= WT_TOTAL) return;
    int j = i;
    if (j < 2048) {
        int n = j >> 5, k = j & 31;
        WT[i] = (k < 16) ? f2bf(nW1[k * 64 + n]) : 0;
        return;
    }
    j -= 2048;
    if (j < 4096) {
        int n = j >> 6, k = j & 63;
        WT[i] = f2bf(nW2[k * 64 + n]);
        return;
    }
    j -= 4096;
    if (j < 3 * LYR_SZ) {
        int l = j / LYR_SZ;  j -= l * LYR_SZ;
        int m = j >> 12;     j &= 4095;
        int n = j >> 6, k = j & 63;
        const float* src;
        if (m == 0)      src = lW1 + (size_t)l * 131 * 64;
        else if (m == 1) src = lW1 + (size_t)l * 131 * 64 + 64 * 64;
        else if (m == 2) src = lW2 + (size_t)l * 4096;
        else if (m == 3) src = gW1 + (size_t)l * 4096;
        else             src = gW2 + (size_t)l * 4096;
        WT[i] = f2bf(src[k * 64 + n]);
        return;
    }
    j -= 3 * LYR_SZ;
    if (j < 2048) {
        int n = j >> 6, k = j & 63;
        WT[i] = f2bf(lin1W[k * 32 + n]);
        return;
    }
    j -= 2048;
    {
        int n = j >> 5, k = j & 31;
        WT[i] = (n < 8) ? f2bf(lin2W[k * 8 + n]) : 0;
    }
}

// ---------------------------------------------------------------------------
// bucket build: per-block LDS histogram -> scan -> per-block counting sort
// pack = (src<<16) | dst  (both < 2^16)
// ---------------------------------------------------------------------------
__global__ __launch_bounds__(256) void kHist(const int* __restrict__ ei,
                                             int* __restrict__ gHist) {
    __shared__ int h[NB];
    int tid = threadIdx.x;
    for (int i = tid; i < NB; i += 256) h[i] = 0;
    __syncthreads();
    int base = blockIdx.x * HEPB;
#pragma unroll
    for (int k = 0; k < HEPB; k += 256) {
        int e = base + k + tid;
        if (e < N_EDGES) atomicAdd(&h[ei[N_EDGES + e] >> 7], 1);
    }
    __syncthreads();
    for (int i = tid; i < NB; i += 256)
        if (h[i]) atomicAdd(&gHist[i], h[i]);
}

__global__ __launch_bounds__(256) void kScanB(const int* __restrict__ gHist,
                                              int* __restrict__ bucketOff,
                                              int* __restrict__ cursor) {
    __shared__ int s0[512], s1[512];
    int tid = threadIdx.x;
    for (int e = tid; e < 512; e += 256) s0[e] = (e < NB) ? gHist[e] : 0;
    __syncthreads();
    int* sp = s0; int* dp = s1;
    for (int off = 1; off < 512; off <<= 1) {
        for (int e = tid; e < 512; e += 256)
            dp[e] = sp[e] + ((e >= off) ? sp[e - off] : 0);
        __syncthreads();
        int* t = sp; sp = dp; dp = t;
    }
    for (int e = tid; e < NB; e += 256) {
        int excl = sp[e] - gHist[e];
        bucketOff[e] = excl;
        cursor[e] = excl;
    }
    if (tid == 0) bucketOff[NB] = sp[NB - 1];
}

__global__ __launch_bounds__(256) void kScat(const int* __restrict__ ei,
                                             int* __restrict__ cursor,
                                             int* __restrict__ packs) {
    __shared__ int sdata[SEPB];
    __shared__ int hist[NB];
    __shared__ int loff[NB + 1];
    __shared__ int gbase[NB];
    __shared__ int sc0[512], sc1[512];
    int tid = threadIdx.x;
    int base = blockIdx.x * SEPB;
    int nE = min(SEPB, N_EDGES - base);

    for (int i = tid; i < NB; i += 256) hist[i] = 0;
    __syncthreads();

    int myPack[SEPB / 256];
    unsigned short myRank[SEPB / 256];
#pragma unroll
    for (int kk = 0; kk < SEPB / 256; ++kk) {
        int e = base + kk * 256 + tid;
        if (e < N_EDGES) {
            int s = ei[e], d = ei[N_EDGES + e];
            myPack[kk] = (s << 16) | d;
            myRank[kk] = (unsigned short)atomicAdd(&hist[d >> 7], 1);
        }
    }
    __syncthreads();

    // scan hist -> loff (exclusive)
    for (int e = tid; e < 512; e += 256) sc0[e] = (e < NB) ? hist[e] : 0;
    __syncthreads();
    int* sp = sc0; int* dp = sc1;
    for (int off = 1; off < 512; off <<= 1) {
        for (int e = tid; e < 512; e += 256)
            dp[e] = sp[e] + ((e >= off) ? sp[e - off] : 0);
        __syncthreads();
        int* t = sp; sp = dp; dp = t;
    }
    for (int e = tid; e < NB; e += 256) loff[e] = sp[e] - hist[e];
    if (tid == 0) loff[NB] = sp[NB - 1];
    __syncthreads();

    // global bases + local reorder
    for (int e = tid; e < NB; e += 256)
        gbase[e] = hist[e] ? atomicAdd(&cursor[e], hist[e]) : 0;
#pragma unroll
    for (int kk = 0; kk < SEPB / 256; ++kk) {
        int e = base + kk * 256 + tid;
        if (e < N_EDGES) {
            int p = myPack[kk];
            int b = (p & 0xffff) >> 7;
            sdata[loff[b] + myRank[kk]] = p;
        }
    }
    __syncthreads();

    // linear burst write (runs of ~21 edges per bucket)
    for (int i = tid; i < nE; i += 256) {
        int p = sdata[i];
        int b = (p & 0xffff) >> 7;
        packs[gbase[b] + (i - loff[b])] = p;
    }
}

// ---------------------------------------------------------------------------
// bucketed aggregation: block = 128-node bucket, LDS f32 bins, ds_add_f32
// aggH[n][ch] = sum_edges relu(u[n][ch] + v[src][ch]); also per-node degree.
// aggH may alias u (uS staged before writes; each block owns its rows).
// ---------------------------------------------------------------------------
__global__ __launch_bounds__(256) void kAggB(
    const int* __restrict__ bucketOff, const int* __restrict__ packs,
    const unsigned short* __restrict__ u, const unsigned short* __restrict__ v,
    unsigned short* __restrict__ aggH, float* __restrict__ degF, int writeDeg) {
    __shared__ float bins[128 * 64];
    __shared__ __align__(16) unsigned short uS[128 * 64];
    __shared__ int degB[128];
    int tid = threadIdx.x, lane = tid & 63, wv = tid >> 6;
    int nbk = blockIdx.x;
    int nodeBase = nbk * 128;
    int nvalid = min(128, N_NODES - nodeBase);

    for (int i = tid; i < 128 * 64; i += 256) bins[i] = 0.f;
    for (int i = tid; i < 128; i += 256) degB[i] = 0;
    const uint4* up = (const uint4*)(u + (size_t)nodeBase * 64);
    for (int i = tid; i < nvalid * 8; i += 256) ((uint4*)uS)[i] = up[i];
    __syncthreads();

    int eb = bucketOff[nbk], ee = bucketOff[nbk + 1];
    int i = eb + wv;
    for (; i + 4 < ee; i += 8) {
        int p0 = packs[i], p1 = packs[i + 4];
        int s0 = ((unsigned)p0) >> 16, s1 = ((unsigned)p1) >> 16;
        int d0 = p0 & 127, d1 = p1 & 127;
        float v0 = bf2f(v[(size_t)s0 * 64 + lane]);
        float v1 = bf2f(v[(size_t)s1 * 64 + lane]);
        float u0 = bf2f(uS[d0 * 64 + lane]);
        float u1 = bf2f(uS[d1 * 64 + lane]);
        atomicAdd(&bins[d0 * 64 + lane], fmaxf(u0 + v0, 0.f));
        atomicAdd(&bins[d1 * 64 + lane], fmaxf(u1 + v1, 0.f));
        if (lane == 0) { atomicAdd(&degB[d0], 1); atomicAdd(&degB[d1], 1); }
    }
    for (; i < ee; i += 4) {
        int p0 = packs[i];
        int s0 = ((unsigned)p0) >> 16;
        int d0 = p0 & 127;
        float v0 = bf2f(v[(size_t)s0 * 64 + lane]);
        float u0 = bf2f(uS[d0 * 64 + lane]);
        atomicAdd(&bins[d0 * 64 + lane], fmaxf(u0 + v0, 0.f));
        if (lane == 0) atomicAdd(&degB[d0], 1);
    }
    __syncthreads();

    for (int i2 = tid; i2 < nvalid * 64; i2 += 256)
        aggH[(size_t)nodeBase * 64 + i2] = f2bf(bins[i2]);
    if (writeDeg)
        for (int i2 = tid; i2 < nvalid; i2 += 256)
            degF[nodeBase + i2] = (float)degB[i2];
}

// ---------------------------------------------------------------------------
// kA: node_lin (16->64 relu ->64) then u = h@W1a, v = h@W1b + pos@W1c + b1
// ---------------------------------------------------------------------------
__global__ __launch_bounds__(256) void kA(
    const float* __restrict__ x, const float* __restrict__ pos,
    const unsigned short* __restrict__ WT,
    const float* __restrict__ nb1, const float* __restrict__ nb2,
    const float* __restrict__ lW1f, const float* __restrict__ lb1,
    unsigned short* __restrict__ u, unsigned short* __restrict__ v) {
    __shared__ unsigned short Xa[64 * XPITCH];
    __shared__ unsigned short Xb[64 * XPITCH];
    __shared__ float posS[192];
    int tid = threadIdx.x;
    int lane = tid & 63;
    int wv = __builtin_amdgcn_readfirstlane(tid >> 6);
    int nodeBase = blockIdx.x * 64;
    int nvalid = min(64, N_NODES - nodeBase);
    int col = lane & 15;

    for (int idx = tid; idx < 64 * 32; idx += 256) {
        int rowi = idx >> 5, k = idx & 31;
        float val = (k < 16 && rowi < nvalid) ? x[(size_t)(nodeBase + rowi) * 16 + k] : 0.f;
        Xa[rowi * XPITCH + k] = f2bf(val);
    }
    for (int idx = tid; idx < 192; idx += 256)
        posS[idx] = (idx < nvalid * 3) ? pos[(size_t)nodeBase * 3 + idx] : 0.f;
    __syncthreads();

#pragma unroll
    for (int nt = 0; nt < 4; ++nt) {
        f32x4 acc = tile_mm<1, 32>(Xa, WT + OFF_NW1T, wv, nt, lane, mk4(nb1[nt * 16 + col]));
        ep_lds(Xb, wv, nt, lane, acc, true);
    }
    __syncthreads();

#pragma unroll
    for (int nt = 0; nt < 4; ++nt) {
        f32x4 acc = tile_mm<2, 64>(Xb, WT + OFF_NW2T, wv, nt, lane, mk4(nb2[nt * 16 + col]));
        ep_lds(Xa, wv, nt, lane, acc, false);
    }
    __syncthreads();

    const unsigned short* aT = WT + OFF_LYR;
    const unsigned short* bT = aT + 4096;
    const float* W1c = lW1f + 128 * 64;

#pragma unroll
    for (int nt = 0; nt < 4; ++nt) {
        f32x4 acc = tile_mm<2, 64>(Xa, aT, wv, nt, lane, mk4(0.f));
        ep_glob(u, nodeBase, nvalid, wv, nt, lane, acc);
    }
#pragma unroll
    for (int nt = 0; nt < 4; ++nt) {
        int ch = nt * 16 + col;
        f32x4 acc = tile_mm<2, 64>(Xa, bT, wv, nt, lane, mk4(lb1[ch]));
        float w0 = W1c[ch], w1 = W1c[64 + ch], w2 = W1c[128 + ch];
        int quad = lane >> 4;
#pragma unroll
        for (int r = 0; r < 4; ++r) {
            int nl = wv * 16 + quad * 4 + r;
            acc[r] += posS[nl * 3] * w0 + posS[nl * 3 + 1] * w1 + posS[nl * 3 + 2] * w2;
        }
        ep_glob(v, nodeBase, nvalid, wv, nt, lane, acc);
    }
}

// ---------------------------------------------------------------------------
// kB (layers 0,1): aggH -> local_W2/global_nn -> h -> next-layer u,v
// ---------------------------------------------------------------------------
__global__ __launch_bounds__(256) void kB(
    const unsigned short* __restrict__ aggH, const float* __restrict__ pos,
    const float* __restrict__ degF, const unsigned short* __restrict__ WT,
    int l,
    const float* __restrict__ lb2, const float* __restrict__ gb1,
    const float* __restrict__ gb2,
    const float* __restrict__ lW1f_next, const float* __restrict__ b1n,
    unsigned short* __restrict__ u, unsigned short* __restrict__ v) {
    __shared__ unsigned short Xa[64 * XPITCH];
    __shared__ unsigned short Xb[64 * XPITCH];
    __shared__ float posS[192];
    __shared__ float degS[64];
    int tid = threadIdx.x;
    int lane = tid & 63;
    int wv = __builtin_amdgcn_readfirstlane(tid >> 6);
    int nodeBase = blockIdx.x * 64;
    int nvalid = min(64, N_NODES - nodeBase);
    int col = lane & 15;
    int quad = lane >> 4;

    const unsigned short* LYR = WT + OFF_LYR + (size_t)l * LYR_SZ;
    const unsigned short* lW2T = LYR + 2 * 4096;
    const unsigned short* gW1T = LYR + 3 * 4096;
    const unsigned short* gW2T = LYR + 4 * 4096;
    const unsigned short* aTn = WT + OFF_LYR + (size_t)(l + 1) * LYR_SZ;
    const unsigned short* bTn = aTn + 4096;

    const uint4* ag = (const uint4*)(aggH + (size_t)nodeBase * 64);
    for (int idx = tid; idx < 512; idx += 256) {
        int rowi = idx >> 3, seg = idx & 7;
        uint4 d = (rowi < nvalid) ? ag[idx] : make_uint4(0u, 0u, 0u, 0u);
        *(uint4*)&Xa[rowi * XPITCH + seg * 8] = d;
    }
    for (int idx = tid; idx < 192; idx += 256)
        posS[idx] = (idx < nvalid * 3) ? pos[(size_t)nodeBase * 3 + idx] : 0.f;
    if (tid < 64)
        degS[tid] = (tid < nvalid) ? degF[nodeBase + tid] : 0.f;
    __syncthreads();

#pragma unroll
    for (int nt = 0; nt < 4; ++nt) {
        float b = lb2[nt * 16 + col];
        f32x4 init;
        float4 dg = *(float4*)&degS[wv * 16 + quad * 4];
        init[0] = dg.x * b; init[1] = dg.y * b; init[2] = dg.z * b; init[3] = dg.w * b;
        f32x4 acc = tile_mm<2, 64>(Xa, lW2T, wv, nt, lane, init);
        ep_lds(Xb, wv, nt, lane, acc, false);
    }
    __syncthreads();

#pragma unroll
    for (int nt = 0; nt < 4; ++nt) {
        f32x4 acc = tile_mm<2, 64>(Xb, gW1T, wv, nt, lane, mk4(gb1[nt * 16 + col]));
        ep_lds(Xa, wv, nt, lane, acc, true);
    }
    __syncthreads();

#pragma unroll
    for (int nt = 0; nt < 4; ++nt) {
        f32x4 acc = tile_mm<2, 64>(Xa, gW2T, wv, nt, lane, mk4(gb2[nt * 16 + col]));
        ep_lds(Xb, wv, nt, lane, acc, true);
    }
    __syncthreads();

#pragma unroll
    for (int nt = 0; nt < 4; ++nt) {
        f32x4 acc = tile_mm<2, 64>(Xb, aTn, wv, nt, lane, mk4(0.f));
        ep_glob(u, nodeBase, nvalid, wv, nt, lane, acc);
    }
    const float* W1c = lW1f_next + 128 * 64;
#pragma unroll
    for (int nt = 0; nt < 4; ++nt) {
        int ch = nt * 16 + col;
        f32x4 acc = tile_mm<2, 64>(Xb, bTn, wv, nt, lane, mk4(b1n[ch]));
        float w0 = W1c[ch], w1 = W1c[64 + ch], w2 = W1c[128 + ch];
#pragma unroll
        for (int r = 0; r < 4; ++r) {
            int nl = wv * 16 + quad * 4 + r;
            acc[r] += posS[nl * 3] * w0 + posS[nl * 3 + 1] * w1 + posS[nl * 3 + 2] * w2;
        }
        ep_glob(v, nodeBase, nvalid, wv, nt, lane, acc);
    }
}

// ---------------------------------------------------------------------------
// kC (layer 2): aggH -> global_nn -> h -> lin1 relu lin2 -> LDS-binned readout
// ---------------------------------------------------------------------------
__global__ __launch_bounds__(256) void kC(
    const unsigned short* __restrict__ aggH, const float* __restrict__ degF,
    const int* __restrict__ batch, const unsigned short* __restrict__ WT,
    const float* __restrict__ lb2, const float* __restrict__ gb1,
    const float* __restrict__ gb2,
    const float* __restrict__ lin1b, const float* __restrict__ lin2b,
    float* __restrict__ out) {
    __shared__ unsigned short Xa[64 * XPITCH];
    __shared__ unsigned short Xb[64 * XPITCH];
    __shared__ float degS[64];
    __shared__ int batchS[64];
    __shared__ float bins[128 * 8];
    int tid = threadIdx.x;
    int lane = tid & 63;
    int wv = __builtin_amdgcn_readfirstlane(tid >> 6);
    int nodeBase = blockIdx.x * 64;
    int nvalid = min(64, N_NODES - nodeBase);
    int col = lane & 15;
    int quad = lane >> 4;

    const unsigned short* LYR = WT + OFF_LYR + 2 * LYR_SZ;
    const unsigned short* lW2T = LYR + 2 * 4096;
    const unsigned short* gW1T = LYR + 3 * 4096;
    const unsigned short* gW2T = LYR + 4 * 4096;
    const unsigned short* lin1T = WT + OFF_LIN1T;
    const unsigned short* lin2T = WT + OFF_LIN2T;

    const uint4* ag = (const uint4*)(aggH + (size_t)nodeBase * 64);
    for (int idx = tid; idx < 512; idx += 256) {
        int rowi = idx >> 3, seg = idx & 7;
        uint4 d = (rowi < nvalid) ? ag[idx] : make_uint4(0u, 0u, 0u, 0u);
        *(uint4*)&Xa[rowi * XPITCH + seg * 8] = d;
    }
    if (tid < 64) {
        degS[tid] = (tid < nvalid) ? degF[nodeBase + tid] : 0.f;
        batchS[tid] = (tid < nvalid) ? batch[nodeBase + tid] : batch[N_NODES - 1];
    }
    for (int idx = tid; idx < 128 * 8; idx += 256) bins[idx] = 0.f;
    __syncthreads();

#pragma unroll
    for (int nt = 0; nt < 4; ++nt) {
        float b = lb2[nt * 16 + col];
        f32x4 init;
        float4 dg = *(float4*)&degS[wv * 16 + quad * 4];
        init[0] = dg.x * b; init[1] = dg.y * b; init[2] = dg.z * b; init[3] = dg.w * b;
        f32x4 acc = tile_mm<2, 64>(Xa, lW2T, wv, nt, lane, init);
        ep_lds(Xb, wv, nt, lane, acc, false);
    }
    __syncthreads();
#pragma unroll
    for (int nt = 0; nt < 4; ++nt) {
        f32x4 acc = tile_mm<2, 64>(Xb, gW1T, wv, nt, lane, mk4(gb1[nt * 16 + col]));
        ep_lds(Xa, wv, nt, lane, acc, true);
    }
    __syncthreads();
#pragma unroll
    for (int nt = 0; nt < 4; ++nt) {
        f32x4 acc = tile_mm<2, 64>(Xa, gW2T, wv, nt, lane, mk4(gb2[nt * 16 + col]));
        ep_lds(Xb, wv, nt, lane, acc, true);
    }
    __syncthreads();

#pragma unroll
    for (int nt = 0; nt < 2; ++nt) {
        f32x4 acc = tile_mm<2, 64>(Xb, lin1T, wv, nt, lane, mk4(lin1b[nt * 16 + col]));
        ep_lds(Xa, wv, nt, lane, acc, true);
    }
    __syncthreads();

    {
        f32x4 acc = tile_mm<1, 32>(Xa, lin2T, wv, 0, lane,
                                   mk4(col < 8 ? lin2b[col] : 0.f));
        int gmin = batch[nodeBase];
        if (col < 8) {
#pragma unroll
            for (int r = 0; r < 4; ++r) {
                int nl = wv * 16 + quad * 4 + r;
                if (nl < nvalid)
                    atomicAdd(&bins[(batchS[nl] - gmin) * 8 + col], acc[r]);
            }
        }
        __syncthreads();
        int nb8 = (batchS[nvalid - 1] - gmin + 1) * 8;
        for (int idx = tid; idx < nb8; idx += 256)
            atomAddF(&out[gmin * 8 + idx], bins[idx]);
    }
}

// ---------------------------------------------------------------------------
// launch
// ---------------------------------------------------------------------------
extern "C" void kernel_launch(void* const* d_in, const int* in_sizes, int n_in,
                              void* d_out, int out_size, void* d_ws, size_t ws_size,
                              hipStream_t stream) {
    const float* x     = (const float*)d_in[0];
    const float* pos   = (const float*)d_in[1];
    const int*   ei    = (const int*)d_in[2];
    const int*   batch = (const int*)d_in[3];
    const float* nW1   = (const float*)d_in[4];
    const float* nb1   = (const float*)d_in[5];
    const float* nW2   = (const float*)d_in[6];
    const float* nb2   = (const float*)d_in[7];
    const float* lW1   = (const float*)d_in[8];
    const float* lb1   = (const float*)d_in[9];
    const float* lW2   = (const float*)d_in[10];
    const float* lb2   = (const float*)d_in[11];
    const float* gW1   = (const float*)d_in[12];
    const float* gb1   = (const float*)d_in[13];
    const float* gW2   = (const float*)d_in[14];
    const float* gb2   = (const float*)d_in[15];
    const float* lin1W = (const float*)d_in[16];
    const float* lin1b = (const float*)d_in[17];
    const float* lin2W = (const float*)d_in[18];
    const float* lin2b = (const float*)d_in[19];
    float* out = (float*)d_out;

    // workspace (u doubles as aggH)
    unsigned short* u  = (unsigned short*)d_ws;          // N*64 bf16
    unsigned short* v  = u + (size_t)N_NODES * 64;       // N*64 bf16
    unsigned short* WT = v + (size_t)N_NODES * 64;       // WT_TOTAL bf16
    float* degF = (float*)(WT + WT_TOTAL);               // N f32
    int* gHist = (int*)(degF + N_NODES);                 // NB
    int* bucketOff = gHist + NB;                         // NB+1
    int* cursor = bucketOff + NB + 1;                    // NB
    int* packs = cursor + NB;                            // E
    unsigned short* aggH = u;

    const int nodeBlocks = (N_NODES + 63) / 64;

    hipMemsetAsync(gHist, 0, NB * sizeof(int), stream);
    hipMemsetAsync(out, 0, (size_t)out_size * sizeof(float), stream);

    kPrep<<<(WT_TOTAL + 255) / 256, 256, 0, stream>>>(nW1, nW2, lW1, lW2, gW1, gW2,
                                                      lin1W, lin2W, WT);
    kHist<<<(N_EDGES + HEPB - 1) / HEPB, 256, 0, stream>>>(ei, gHist);
    kScanB<<<1, 256, 0, stream>>>(gHist, bucketOff, cursor);
    kScat<<<(N_EDGES + SEPB - 1) / SEPB, 256, 0, stream>>>(ei, cursor, packs);

    kA<<<nodeBlocks, 256, 0, stream>>>(x, pos, WT, nb1, nb2, lW1, lb1, u, v);

    for (int l = 0; l < 3; ++l) {
        kAggB<<<NB, 256, 0, stream>>>(bucketOff, packs, u, v, aggH, degF, l == 0);
        if (l < 2) {
            kB<<<nodeBlocks, 256, 0, stream>>>(
                aggH, pos, degF, WT, l,
                lb2 + l * 64, gb1 + l * 64, gb2 + l * 64,
                lW1 + (size_t)(l + 1) * 131 * 64, lb1 + (l + 1) * 64,
                u, v);
        } else {
            kC<<<nodeBlocks, 256, 0, stream>>>(
                aggH, degF, batch, WT,
                lb2 + l * 64, gb1 + l * 64, gb2 + l * 64,
                lin1b, lin2b, out);
        }
    }
}

// Round 6
// 336.775 us; speedup vs baseline: 3.9156x; 3.9156x over previous
//
#include <hip/hip_runtime.h>

#define N_NODES 50000
#define N_EDGES 800000
#define NGRAPH  128
#define XPITCH  72   // ushort pitch for 64-wide LDS activation rows (16B-aligned, 2-way banks)
#define NB      391  // dst buckets of 128 nodes
#define HEPB    4096 // edges per block, histogram kernel
#define SEPB    8192 // edges per block, scatter kernel

typedef short bf16x8 __attribute__((ext_vector_type(8)));
typedef float f32x4  __attribute__((ext_vector_type(4)));

// ---------------------------------------------------------------------------
// helpers
// ---------------------------------------------------------------------------

__device__ __forceinline__ float atomAddF(float* p, float v) {
#if defined(__gfx950__) || defined(__AMDGCN__)
    return unsafeAtomicAdd(p, v);
#else
    return atomicAdd(p, v);
#endif
}

__device__ __forceinline__ unsigned short f2bf(float x) {  // RNE f32 -> bf16
    unsigned u = __builtin_bit_cast(unsigned, x);
    u += 0x7fffu + ((u >> 16) & 1u);
    return (unsigned short)(u >> 16);
}
__device__ __forceinline__ float bf2f(unsigned short h) {
    return __builtin_bit_cast(float, (unsigned)h << 16);
}

// One 16x16 C-tile: acc += X[16mt..+16][K] @ WT^T[16nt..+16] over NKC k-chunks.
template<int NKC, int KROW>
__device__ __forceinline__ f32x4 tile_mm(const unsigned short* __restrict__ Xlds,
                                         const unsigned short* __restrict__ WT,
                                         int mt, int nt, int lane, f32x4 acc) {
    int col  = lane & 15;
    int quad = lane >> 4;
    const unsigned short* xp = Xlds + (mt * 16 + col) * XPITCH + quad * 8;
    const unsigned short* wp = WT + (nt * 16 + col) * KROW + quad * 8;
#pragma unroll
    for (int c = 0; c < NKC; ++c) {
        bf16x8 a = *(const bf16x8*)(xp + c * 32);
        bf16x8 b = *(const bf16x8*)(wp + c * 32);
        acc = __builtin_amdgcn_mfma_f32_16x16x32_bf16(a, b, acc, 0, 0, 0);
    }
    return acc;
}

__device__ __forceinline__ f32x4 mk4(float b) { f32x4 a = {b, b, b, b}; return a; }

// C/D layout: col=lane&15 (=n offset), row=quad*4+reg (=m offset)
__device__ __forceinline__ void ep_lds(unsigned short* __restrict__ Xo, int wv, int nt,
                                       int lane, f32x4 acc, bool relu) {
    int col = lane & 15, quad = lane >> 4;
#pragma unroll
    for (int r = 0; r < 4; ++r) {
        float xv = acc[r];
        if (relu) xv = fmaxf(xv, 0.f);
        Xo[(wv * 16 + quad * 4 + r) * XPITCH + nt * 16 + col] = f2bf(xv);
    }
}

__device__ __forceinline__ void ep_glob(unsigned short* __restrict__ g, int nodeBase,
                                        int nvalid, int wv, int nt, int lane, f32x4 acc) {
    int col = lane & 15, quad = lane >> 4;
#pragma unroll
    for (int r = 0; r < 4; ++r) {
        int nl = wv * 16 + quad * 4 + r;
        if (nl < nvalid)
            g[(size_t)(nodeBase + nl) * 64 + nt * 16 + col] = f2bf(acc[r]);
    }
}

// ---------------------------------------------------------------------------
// weight prep (transpose + bf16 into B-operand layout)
// ---------------------------------------------------------------------------
#define OFF_NW1T  0
#define OFF_NW2T  2048
#define OFF_LYR   6144
#define LYR_SZ    20480
#define OFF_LIN1T 67584
#define OFF_LIN2T 69632
#define WT_TOTAL  70144

__global__ __launch_bounds__(256) void kPrep(
    const float* __restrict__ nW1, const float* __restrict__ nW2,
    const float* __restrict__ lW1, const float* __restrict__ lW2,
    const float* __restrict__ gW1, const float* __restrict__ gW2,
    const float* __restrict__ lin1W, const float* __restrict__ lin2W,
    unsigned short* __restrict__ WT) {
    int i = blockIdx.x * 256 + threadIdx.x;
    if (i >= WT_TOTAL) return;
    int j = i;
    if (j < 2048) {
        int n = j >> 5, k = j & 31;
        WT[i] = (k < 16) ? f2bf(nW1[k * 64 + n]) : 0;
        return;
    }
    j -= 2048;
    if (j < 4096) {
        int n = j >> 6, k = j & 63;
        WT[i] = f2bf(nW2[k * 64 + n]);
        return;
    }
    j -= 4096;
    if (j < 3 * LYR_SZ) {
        int l = j / LYR_SZ;  j -= l * LYR_SZ;
        int m = j >> 12;     j &= 4095;
        int n = j >> 6, k = j & 63;
        const float* src;
        if (m == 0)      src = lW1 + (size_t)l * 131 * 64;
        else if (m == 1) src = lW1 + (size_t)l * 131 * 64 + 64 * 64;
        else if (m == 2) src = lW2 + (size_t)l * 4096;
        else if (m == 3) src = gW1 + (size_t)l * 4096;
        else             src = gW2 + (size_t)l * 4096;
        WT[i] = f2bf(src[k * 64 + n]);
        return;
    }
    j -= 3 * LYR_SZ;
    if (j < 2048) {
        int n = j >> 6, k = j & 63;
        WT[i] = f2bf(lin1W[k * 32 + n]);
        return;
    }
    j -= 2048;
    {
        int n = j >> 5, k = j & 31;
        WT[i] = (n < 8) ? f2bf(lin2W[k * 8 + n]) : 0;
    }
}

// ---------------------------------------------------------------------------
// bucket build: per-block LDS histogram -> scan -> bucket-grouped packs
// pack = (src<<16) | dst  (both < 2^16)
// ---------------------------------------------------------------------------
__global__ __launch_bounds__(256) void kHist(const int* __restrict__ ei,
                                             int* __restrict__ gHist) {
    __shared__ int h[NB];
    int tid = threadIdx.x;
    for (int i = tid; i < NB; i += 256) h[i] = 0;
    __syncthreads();
    int base = blockIdx.x * HEPB;
#pragma unroll
    for (int k = 0; k < HEPB; k += 256) {
        int e = base + k + tid;
        if (e < N_EDGES) atomicAdd(&h[ei[N_EDGES + e] >> 7], 1);
    }
    __syncthreads();
    for (int i = tid; i < NB; i += 256)
        if (h[i]) atomicAdd(&gHist[i], h[i]);
}

__global__ __launch_bounds__(256) void kScanB(const int* __restrict__ gHist,
                                              int* __restrict__ bucketOff,
                                              int* __restrict__ cursor) {
    __shared__ int s0[512], s1[512];
    int tid = threadIdx.x;
    for (int e = tid; e < 512; e += 256) s0[e] = (e < NB) ? gHist[e] : 0;
    __syncthreads();
    int* sp = s0; int* dp = s1;
    for (int off = 1; off < 512; off <<= 1) {
        for (int e = tid; e < 512; e += 256)
            dp[e] = sp[e] + ((e >= off) ? sp[e - off] : 0);
        __syncthreads();
        int* t = sp; sp = dp; dp = t;
    }
    for (int e = tid; e < NB; e += 256) {
        int excl = sp[e] - gHist[e];
        bucketOff[e] = excl;
        cursor[e] = excl;
    }
    if (tid == 0) bucketOff[NB] = sp[NB - 1];
}

__global__ __launch_bounds__(256) void kScat(const int* __restrict__ ei,
                                             int* __restrict__ cursor,
                                             int* __restrict__ packs) {
    __shared__ int sdata[SEPB];
    __shared__ int hist[NB];
    __shared__ int loff[NB + 1];
    __shared__ int gbase[NB];
    __shared__ int sc0[512], sc1[512];
    int tid = threadIdx.x;
    int base = blockIdx.x * SEPB;
    int nE = min(SEPB, N_EDGES - base);

    for (int i = tid; i < NB; i += 256) hist[i] = 0;
    __syncthreads();

    int myPack[SEPB / 256];
    unsigned short myRank[SEPB / 256];
#pragma unroll
    for (int kk = 0; kk < SEPB / 256; ++kk) {
        int e = base + kk * 256 + tid;
        if (e < N_EDGES) {
            int s = ei[e], d = ei[N_EDGES + e];
            myPack[kk] = (s << 16) | d;
            myRank[kk] = (unsigned short)atomicAdd(&hist[d >> 7], 1);
        }
    }
    __syncthreads();

    for (int e = tid; e < 512; e += 256) sc0[e] = (e < NB) ? hist[e] : 0;
    __syncthreads();
    int* sp = sc0; int* dp = sc1;
    for (int off = 1; off < 512; off <<= 1) {
        for (int e = tid; e < 512; e += 256)
            dp[e] = sp[e] + ((e >= off) ? sp[e - off] : 0);
        __syncthreads();
        int* t = sp; sp = dp; dp = t;
    }
    for (int e = tid; e < NB; e += 256) loff[e] = sp[e] - hist[e];
    if (tid == 0) loff[NB] = sp[NB - 1];
    __syncthreads();

    for (int e = tid; e < NB; e += 256)
        gbase[e] = hist[e] ? atomicAdd(&cursor[e], hist[e]) : 0;
#pragma unroll
    for (int kk = 0; kk < SEPB / 256; ++kk) {
        int e = base + kk * 256 + tid;
        if (e < N_EDGES) {
            int p = myPack[kk];
            int b = (p & 0xffff) >> 7;
            sdata[loff[b] + myRank[kk]] = p;
        }
    }
    __syncthreads();

    for (int i = tid; i < nE; i += 256) {
        int p = sdata[i];
        int b = (p & 0xffff) >> 7;
        packs[gbase[b] + (i - loff[b])] = p;
    }
}

// ---------------------------------------------------------------------------
// per-bucket counting sort -> full per-node CSR (srcList ushort) + rowPtr
// all writes land in the block's own ~4KB window (L2-resident, no amplification)
// ---------------------------------------------------------------------------
__global__ __launch_bounds__(256) void kSort(
    const int* __restrict__ bucketOff, const int* __restrict__ packs,
    unsigned short* __restrict__ srcList, int* __restrict__ rowPtr) {
    __shared__ int hist[128];
    __shared__ int cur[128];
    __shared__ int sc0[128], sc1[128];
    int tid = threadIdx.x;
    int nbk = blockIdx.x;
    int nodeBase = nbk * 128;
    int nvalid = min(128, N_NODES - nodeBase);
    int eb = bucketOff[nbk], ee = bucketOff[nbk + 1];

    if (tid < 128) hist[tid] = 0;
    __syncthreads();
    for (int i = eb + tid; i < ee; i += 256)
        atomicAdd(&hist[packs[i] & 127], 1);
    __syncthreads();

    if (tid < 128) sc0[tid] = hist[tid];
    __syncthreads();
    int* sp = sc0; int* dp = sc1;
    for (int off = 1; off < 128; off <<= 1) {
        if (tid < 128) dp[tid] = sp[tid] + ((tid >= off) ? sp[tid - off] : 0);
        __syncthreads();
        int* t = sp; sp = dp; dp = t;
    }
    if (tid < 128) {
        int excl = eb + sp[tid] - hist[tid];
        if (tid < nvalid) rowPtr[nodeBase + tid] = excl;
        cur[tid] = excl;
    }
    if (nbk == NB - 1 && tid == 0) rowPtr[N_NODES] = ee;
    __syncthreads();

    for (int i = eb + tid; i < ee; i += 256) {
        int p = packs[i];
        int pos = atomicAdd(&cur[p & 127], 1);
        srcList[pos] = (unsigned short)(((unsigned)p) >> 16);
    }
}

// ---------------------------------------------------------------------------
// aggregation: one wave per node, lane = channel; zero atomics
// aggH[n][ch] = sum relu(u[n][ch] + v[src][ch]); aggH may alias u
// ---------------------------------------------------------------------------
__global__ __launch_bounds__(256) void kAgg(const int* __restrict__ rowPtr,
                                            const unsigned short* __restrict__ srcList,
                                            const unsigned short* __restrict__ u,
                                            const unsigned short* __restrict__ v,
                                            unsigned short* __restrict__ aggH) {
    int gt = blockIdx.x * 256 + threadIdx.x;
    int n = gt >> 6;
    int lane = gt & 63;
    if (n >= N_NODES) return;
    float ut = bf2f(u[(size_t)n * 64 + lane]);
    int b = rowPtr[n], e = rowPtr[n + 1];
    float acc = 0.f;
    int i = b;
    for (; i + 3 < e; i += 4) {
        int s0 = srcList[i], s1 = srcList[i + 1];
        int s2 = srcList[i + 2], s3 = srcList[i + 3];
        float v0 = bf2f(v[(size_t)s0 * 64 + lane]);
        float v1 = bf2f(v[(size_t)s1 * 64 + lane]);
        float v2 = bf2f(v[(size_t)s2 * 64 + lane]);
        float v3 = bf2f(v[(size_t)s3 * 64 + lane]);
        acc += fmaxf(ut + v0, 0.f) + fmaxf(ut + v1, 0.f)
             + fmaxf(ut + v2, 0.f) + fmaxf(ut + v3, 0.f);
    }
    for (; i < e; ++i)
        acc += fmaxf(ut + bf2f(v[(size_t)srcList[i] * 64 + lane]), 0.f);
    aggH[(size_t)n * 64 + lane] = f2bf(acc);
}

// ---------------------------------------------------------------------------
// kA: node_lin (16->64 relu ->64) then u = h@W1a, v = h@W1b + pos@W1c + b1
// ---------------------------------------------------------------------------
__global__ __launch_bounds__(256) void kA(
    const float* __restrict__ x, const float* __restrict__ pos,
    const unsigned short* __restrict__ WT,
    const float* __restrict__ nb1, const float* __restrict__ nb2,
    const float* __restrict__ lW1f, const float* __restrict__ lb1,
    unsigned short* __restrict__ u, unsigned short* __restrict__ v) {
    __shared__ unsigned short Xa[64 * XPITCH];
    __shared__ unsigned short Xb[64 * XPITCH];
    __shared__ float posS[192];
    int tid = threadIdx.x;
    int lane = tid & 63;
    int wv = __builtin_amdgcn_readfirstlane(tid >> 6);
    int nodeBase = blockIdx.x * 64;
    int nvalid = min(64, N_NODES - nodeBase);
    int col = lane & 15;

    for (int idx = tid; idx < 64 * 32; idx += 256) {
        int rowi = idx >> 5, k = idx & 31;
        float val = (k < 16 && rowi < nvalid) ? x[(size_t)(nodeBase + rowi) * 16 + k] : 0.f;
        Xa[rowi * XPITCH + k] = f2bf(val);
    }
    for (int idx = tid; idx < 192; idx += 256)
        posS[idx] = (idx < nvalid * 3) ? pos[(size_t)nodeBase * 3 + idx] : 0.f;
    __syncthreads();

#pragma unroll
    for (int nt = 0; nt < 4; ++nt) {
        f32x4 acc = tile_mm<1, 32>(Xa, WT + OFF_NW1T, wv, nt, lane, mk4(nb1[nt * 16 + col]));
        ep_lds(Xb, wv, nt, lane, acc, true);
    }
    __syncthreads();

#pragma unroll
    for (int nt = 0; nt < 4; ++nt) {
        f32x4 acc = tile_mm<2, 64>(Xb, WT + OFF_NW2T, wv, nt, lane, mk4(nb2[nt * 16 + col]));
        ep_lds(Xa, wv, nt, lane, acc, false);
    }
    __syncthreads();

    const unsigned short* aT = WT + OFF_LYR;
    const unsigned short* bT = aT + 4096;
    const float* W1c = lW1f + 128 * 64;

#pragma unroll
    for (int nt = 0; nt < 4; ++nt) {
        f32x4 acc = tile_mm<2, 64>(Xa, aT, wv, nt, lane, mk4(0.f));
        ep_glob(u, nodeBase, nvalid, wv, nt, lane, acc);
    }
#pragma unroll
    for (int nt = 0; nt < 4; ++nt) {
        int ch = nt * 16 + col;
        f32x4 acc = tile_mm<2, 64>(Xa, bT, wv, nt, lane, mk4(lb1[ch]));
        float w0 = W1c[ch], w1 = W1c[64 + ch], w2 = W1c[128 + ch];
        int quad = lane >> 4;
#pragma unroll
        for (int r = 0; r < 4; ++r) {
            int nl = wv * 16 + quad * 4 + r;
            acc[r] += posS[nl * 3] * w0 + posS[nl * 3 + 1] * w1 + posS[nl * 3 + 2] * w2;
        }
        ep_glob(v, nodeBase, nvalid, wv, nt, lane, acc);
    }
}

// ---------------------------------------------------------------------------
// kB (layers 0,1): aggH -> local_W2/global_nn -> h -> next-layer u,v
// ---------------------------------------------------------------------------
__global__ __launch_bounds__(256) void kB(
    const unsigned short* __restrict__ aggH, const float* __restrict__ pos,
    const int* __restrict__ rowPtr, const unsigned short* __restrict__ WT,
    int l,
    const float* __restrict__ lb2, const float* __restrict__ gb1,
    const float* __restrict__ gb2,
    const float* __restrict__ lW1f_next, const float* __restrict__ b1n,
    unsigned short* __restrict__ u, unsigned short* __restrict__ v) {
    __shared__ unsigned short Xa[64 * XPITCH];
    __shared__ unsigned short Xb[64 * XPITCH];
    __shared__ float posS[192];
    __shared__ float degS[64];
    int tid = threadIdx.x;
    int lane = tid & 63;
    int wv = __builtin_amdgcn_readfirstlane(tid >> 6);
    int nodeBase = blockIdx.x * 64;
    int nvalid = min(64, N_NODES - nodeBase);
    int col = lane & 15;
    int quad = lane >> 4;

    const unsigned short* LYR = WT + OFF_LYR + (size_t)l * LYR_SZ;
    const unsigned short* lW2T = LYR + 2 * 4096;
    const unsigned short* gW1T = LYR + 3 * 4096;
    const unsigned short* gW2T = LYR + 4 * 4096;
    const unsigned short* aTn = WT + OFF_LYR + (size_t)(l + 1) * LYR_SZ;
    const unsigned short* bTn = aTn + 4096;

    const uint4* ag = (const uint4*)(aggH + (size_t)nodeBase * 64);
    for (int idx = tid; idx < 512; idx += 256) {
        int rowi = idx >> 3, seg = idx & 7;
        uint4 d = (rowi < nvalid) ? ag[idx] : make_uint4(0u, 0u, 0u, 0u);
        *(uint4*)&Xa[rowi * XPITCH + seg * 8] = d;
    }
    for (int idx = tid; idx < 192; idx += 256)
        posS[idx] = (idx < nvalid * 3) ? pos[(size_t)nodeBase * 3 + idx] : 0.f;
    if (tid < 64)
        degS[tid] = (tid < nvalid)
            ? (float)(rowPtr[nodeBase + tid + 1] - rowPtr[nodeBase + tid]) : 0.f;
    __syncthreads();

#pragma unroll
    for (int nt = 0; nt < 4; ++nt) {
        float b = lb2[nt * 16 + col];
        f32x4 init;
        float4 dg = *(float4*)&degS[wv * 16 + quad * 4];
        init[0] = dg.x * b; init[1] = dg.y * b; init[2] = dg.z * b; init[3] = dg.w * b;
        f32x4 acc = tile_mm<2, 64>(Xa, lW2T, wv, nt, lane, init);
        ep_lds(Xb, wv, nt, lane, acc, false);
    }
    __syncthreads();

#pragma unroll
    for (int nt = 0; nt < 4; ++nt) {
        f32x4 acc = tile_mm<2, 64>(Xb, gW1T, wv, nt, lane, mk4(gb1[nt * 16 + col]));
        ep_lds(Xa, wv, nt, lane, acc, true);
    }
    __syncthreads();

#pragma unroll
    for (int nt = 0; nt < 4; ++nt) {
        f32x4 acc = tile_mm<2, 64>(Xa, gW2T, wv, nt, lane, mk4(gb2[nt * 16 + col]));
        ep_lds(Xb, wv, nt, lane, acc, true);
    }
    __syncthreads();

#pragma unroll
    for (int nt = 0; nt < 4; ++nt) {
        f32x4 acc = tile_mm<2, 64>(Xb, aTn, wv, nt, lane, mk4(0.f));
        ep_glob(u, nodeBase, nvalid, wv, nt, lane, acc);
    }
    const float* W1c = lW1f_next + 128 * 64;
#pragma unroll
    for (int nt = 0; nt < 4; ++nt) {
        int ch = nt * 16 + col;
        f32x4 acc = tile_mm<2, 64>(Xb, bTn, wv, nt, lane, mk4(b1n[ch]));
        float w0 = W1c[ch], w1 = W1c[64 + ch], w2 = W1c[128 + ch];
#pragma unroll
        for (int r = 0; r < 4; ++r) {
            int nl = wv * 16 + quad * 4 + r;
            acc[r] += posS[nl * 3] * w0 + posS[nl * 3 + 1] * w1 + posS[nl * 3 + 2] * w2;
        }
        ep_glob(v, nodeBase, nvalid, wv, nt, lane, acc);
    }
}

// ---------------------------------------------------------------------------
// kC (layer 2): aggH -> global_nn -> h -> lin1 relu lin2 -> LDS-binned readout
// ---------------------------------------------------------------------------
__global__ __launch_bounds__(256) void kC(
    const unsigned short* __restrict__ aggH, const int* __restrict__ rowPtr,
    const int* __restrict__ batch, const unsigned short* __restrict__ WT,
    const float* __restrict__ lb2, const float* __restrict__ gb1,
    const float* __restrict__ gb2,
    const float* __restrict__ lin1b, const float* __restrict__ lin2b,
    float* __restrict__ out) {
    __shared__ unsigned short Xa[64 * XPITCH];
    __shared__ unsigned short Xb[64 * XPITCH];
    __shared__ float degS[64];
    __shared__ int batchS[64];
    __shared__ float bins[128 * 8];
    int tid = threadIdx.x;
    int lane = tid & 63;
    int wv = __builtin_amdgcn_readfirstlane(tid >> 6);
    int nodeBase = blockIdx.x * 64;
    int nvalid = min(64, N_NODES - nodeBase);
    int col = lane & 15;
    int quad = lane >> 4;

    const unsigned short* LYR = WT + OFF_LYR + 2 * LYR_SZ;
    const unsigned short* lW2T = LYR + 2 * 4096;
    const unsigned short* gW1T = LYR + 3 * 4096;
    const unsigned short* gW2T = LYR + 4 * 4096;
    const unsigned short* lin1T = WT + OFF_LIN1T;
    const unsigned short* lin2T = WT + OFF_LIN2T;

    const uint4* ag = (const uint4*)(aggH + (size_t)nodeBase * 64);
    for (int idx = tid; idx < 512; idx += 256) {
        int rowi = idx >> 3, seg = idx & 7;
        uint4 d = (rowi < nvalid) ? ag[idx] : make_uint4(0u, 0u, 0u, 0u);
        *(uint4*)&Xa[rowi * XPITCH + seg * 8] = d;
    }
    if (tid < 64) {
        degS[tid] = (tid < nvalid)
            ? (float)(rowPtr[nodeBase + tid + 1] - rowPtr[nodeBase + tid]) : 0.f;
        batchS[tid] = (tid < nvalid) ? batch[nodeBase + tid] : batch[N_NODES - 1];
    }
    for (int idx = tid; idx < 128 * 8; idx += 256) bins[idx] = 0.f;
    __syncthreads();

#pragma unroll
    for (int nt = 0; nt < 4; ++nt) {
        float b = lb2[nt * 16 + col];
        f32x4 init;
        float4 dg = *(float4*)&degS[wv * 16 + quad * 4];
        init[0] = dg.x * b; init[1] = dg.y * b; init[2] = dg.z * b; init[3] = dg.w * b;
        f32x4 acc = tile_mm<2, 64>(Xa, lW2T, wv, nt, lane, init);
        ep_lds(Xb, wv, nt, lane, acc, false);
    }
    __syncthreads();
#pragma unroll
    for (int nt = 0; nt < 4; ++nt) {
        f32x4 acc = tile_mm<2, 64>(Xb, gW1T, wv, nt, lane, mk4(gb1[nt * 16 + col]));
        ep_lds(Xa, wv, nt, lane, acc, true);
    }
    __syncthreads();
#pragma unroll
    for (int nt = 0; nt < 4; ++nt) {
        f32x4 acc = tile_mm<2, 64>(Xa, gW2T, wv, nt, lane, mk4(gb2[nt * 16 + col]));
        ep_lds(Xb, wv, nt, lane, acc, true);
    }
    __syncthreads();

#pragma unroll
    for (int nt = 0; nt < 2; ++nt) {
        f32x4 acc = tile_mm<2, 64>(Xb, lin1T, wv, nt, lane, mk4(lin1b[nt * 16 + col]));
        ep_lds(Xa, wv, nt, lane, acc, true);
    }
    __syncthreads();

    {
        f32x4 acc = tile_mm<1, 32>(Xa, lin2T, wv, 0, lane,
                                   mk4(col < 8 ? lin2b[col] : 0.f));
        int gmin = batch[nodeBase];
        if (col < 8) {
#pragma unroll
            for (int r = 0; r < 4; ++r) {
                int nl = wv * 16 + quad * 4 + r;
                if (nl < nvalid)
                    atomicAdd(&bins[(batchS[nl] - gmin) * 8 + col], acc[r]);
            }
        }
        __syncthreads();
        int nb8 = (batchS[nvalid - 1] - gmin + 1) * 8;
        for (int idx = tid; idx < nb8; idx += 256)
            atomAddF(&out[gmin * 8 + idx], bins[idx]);
    }
}

// ---------------------------------------------------------------------------
// launch
// ---------------------------------------------------------------------------
extern "C" void kernel_launch(void* const* d_in, const int* in_sizes, int n_in,
                              void* d_out, int out_size, void* d_ws, size_t ws_size,
                              hipStream_t stream) {
    const float* x     = (const float*)d_in[0];
    const float* pos   = (const float*)d_in[1];
    const int*   ei    = (const int*)d_in[2];
    const int*   batch = (const int*)d_in[3];
    const float* nW1   = (const float*)d_in[4];
    const float* nb1   = (const float*)d_in[5];
    const float* nW2   = (const float*)d_in[6];
    const float* nb2   = (const float*)d_in[7];
    const float* lW1   = (const float*)d_in[8];
    const float* lb1   = (const float*)d_in[9];
    const float* lW2   = (const float*)d_in[10];
    const float* lb2   = (const float*)d_in[11];
    const float* gW1   = (const float*)d_in[12];
    const float* gb1   = (const float*)d_in[13];
    const float* gW2   = (const float*)d_in[14];
    const float* gb2   = (const float*)d_in[15];
    const float* lin1W = (const float*)d_in[16];
    const float* lin1b = (const float*)d_in[17];
    const float* lin2W = (const float*)d_in[18];
    const float* lin2b = (const float*)d_in[19];
    float* out = (float*)d_out;

    // workspace (u doubles as aggH)
    unsigned short* u  = (unsigned short*)d_ws;          // N*64 bf16
    unsigned short* v  = u + (size_t)N_NODES * 64;       // N*64 bf16
    unsigned short* WT = v + (size_t)N_NODES * 64;       // WT_TOTAL bf16
    int* gHist = (int*)(WT + WT_TOTAL);                  // NB
    int* bucketOff = gHist + NB;                         // NB+1
    int* cursor = bucketOff + NB + 1;                    // NB
    int* rowPtr = cursor + NB;                           // N+1
    int* packs = rowPtr + N_NODES + 1;                   // E int
    unsigned short* srcList = (unsigned short*)(packs + N_EDGES); // E ushort
    unsigned short* aggH = u;

    const int nodeBlocks = (N_NODES + 63) / 64;
    const int aggBlocks  = (N_NODES * 64 + 255) / 256;

    hipMemsetAsync(gHist, 0, NB * sizeof(int), stream);
    hipMemsetAsync(out, 0, (size_t)out_size * sizeof(float), stream);

    kPrep<<<(WT_TOTAL + 255) / 256, 256, 0, stream>>>(nW1, nW2, lW1, lW2, gW1, gW2,
                                                      lin1W, lin2W, WT);
    kHist<<<(N_EDGES + HEPB - 1) / HEPB, 256, 0, stream>>>(ei, gHist);
    kScanB<<<1, 256, 0, stream>>>(gHist, bucketOff, cursor);
    kScat<<<(N_EDGES + SEPB - 1) / SEPB, 256, 0, stream>>>(ei, cursor, packs);
    kSort<<<NB, 256, 0, stream>>>(bucketOff, packs, srcList, rowPtr);

    kA<<<nodeBlocks, 256, 0, stream>>>(x, pos, WT, nb1, nb2, lW1, lb1, u, v);

    for (int l = 0; l < 3; ++l) {
        kAgg<<<aggBlocks, 256, 0, stream>>>(rowPtr, srcList, u, v, aggH);
        if (l < 2) {
            kB<<<nodeBlocks, 256, 0, stream>>>(
                aggH, pos, rowPtr, WT, l,
                lb2 + l * 64, gb1 + l * 64, gb2 + l * 64,
                lW1 + (size_t)(l + 1) * 131 * 64, lb1 + (l + 1) * 64,
                u, v);
        } else {
            kC<<<nodeBlocks, 256, 0, stream>>>(
                aggH, rowPtr, batch, WT,
                lb2 + l * 64, gb1 + l * 64, gb2 + l * 64,
                lin1b, lin2b, out);
        }
    }
}

// Round 7
// 311.565 us; speedup vs baseline: 4.2324x; 1.0809x over previous
//
#include <hip/hip_runtime.h>

#define N_NODES 50000
#define N_EDGES 800000
#define NGRAPH  128
#define XPITCH  72   // ushort pitch for 64-wide LDS activation rows (16B-aligned, 2-way banks)
#define NB      391  // dst buckets of 128 nodes
#define HEPB    4096 // edges per block, histogram kernel
#define SEPB    8192 // edges per block, scatter kernel

typedef short bf16x8 __attribute__((ext_vector_type(8)));
typedef float f32x4  __attribute__((ext_vector_type(4)));

// ---------------------------------------------------------------------------
// helpers
// ---------------------------------------------------------------------------

__device__ __forceinline__ float atomAddF(float* p, float v) {
#if defined(__gfx950__) || defined(__AMDGCN__)
    return unsafeAtomicAdd(p, v);
#else
    return atomicAdd(p, v);
#endif
}

__device__ __forceinline__ unsigned short f2bf(float x) {  // RNE f32 -> bf16
    unsigned u = __builtin_bit_cast(unsigned, x);
    u += 0x7fffu + ((u >> 16) & 1u);
    return (unsigned short)(u >> 16);
}
__device__ __forceinline__ float bf2f(unsigned short h) {
    return __builtin_bit_cast(float, (unsigned)h << 16);
}

// One 16x16 C-tile: acc += X[16mt..+16][K] @ WT^T[16nt..+16] over NKC k-chunks.
template<int NKC, int KROW>
__device__ __forceinline__ f32x4 tile_mm(const unsigned short* __restrict__ Xlds,
                                         const unsigned short* __restrict__ WT,
                                         int mt, int nt, int lane, f32x4 acc) {
    int col  = lane & 15;
    int quad = lane >> 4;
    const unsigned short* xp = Xlds + (mt * 16 + col) * XPITCH + quad * 8;
    const unsigned short* wp = WT + (nt * 16 + col) * KROW + quad * 8;
#pragma unroll
    for (int c = 0; c < NKC; ++c) {
        bf16x8 a = *(const bf16x8*)(xp + c * 32);
        bf16x8 b = *(const bf16x8*)(wp + c * 32);
        acc = __builtin_amdgcn_mfma_f32_16x16x32_bf16(a, b, acc, 0, 0, 0);
    }
    return acc;
}

__device__ __forceinline__ f32x4 mk4(float b) { f32x4 a = {b, b, b, b}; return a; }

// C/D layout: col=lane&15 (=n offset), row=quad*4+reg (=m offset)
__device__ __forceinline__ void ep_lds(unsigned short* __restrict__ Xo, int wv, int nt,
                                       int lane, f32x4 acc, bool relu) {
    int col = lane & 15, quad = lane >> 4;
#pragma unroll
    for (int r = 0; r < 4; ++r) {
        float xv = acc[r];
        if (relu) xv = fmaxf(xv, 0.f);
        Xo[(wv * 16 + quad * 4 + r) * XPITCH + nt * 16 + col] = f2bf(xv);
    }
}

__device__ __forceinline__ void ep_glob(unsigned short* __restrict__ g, int nodeBase,
                                        int nvalid, int wv, int nt, int lane, f32x4 acc) {
    int col = lane & 15, quad = lane >> 4;
#pragma unroll
    for (int r = 0; r < 4; ++r) {
        int nl = wv * 16 + quad * 4 + r;
        if (nl < nvalid)
            g[(size_t)(nodeBase + nl) * 64 + nt * 16 + col] = f2bf(acc[r]);
    }
}

// ---------------------------------------------------------------------------
// weight prep (transpose + bf16 into B-operand layout)
// ---------------------------------------------------------------------------
#define OFF_NW1T  0
#define OFF_NW2T  2048
#define OFF_LYR   6144
#define LYR_SZ    20480
#define OFF_LIN1T 67584
#define OFF_LIN2T 69632
#define WT_TOTAL  70144

__global__ __launch_bounds__(256) void kPrep(
    const float* __restrict__ nW1, const float* __restrict__ nW2,
    const float* __restrict__ lW1, const float* __restrict__ lW2,
    const float* __restrict__ gW1, const float* __restrict__ gW2,
    const float* __restrict__ lin1W, const float* __restrict__ lin2W,
    unsigned short* __restrict__ WT) {
    int i = blockIdx.x * 256 + threadIdx.x;
    if (i >= WT_TOTAL) return;
    int j = i;
    if (j < 2048) {
        int n = j >> 5, k = j & 31;
        WT[i] = (k < 16) ? f2bf(nW1[k * 64 + n]) : 0;
        return;
    }
    j -= 2048;
    if (j < 4096) {
        int n = j >> 6, k = j & 63;
        WT[i] = f2bf(nW2[k * 64 + n]);
        return;
    }
    j -= 4096;
    if (j < 3 * LYR_SZ) {
        int l = j / LYR_SZ;  j -= l * LYR_SZ;
        int m = j >> 12;     j &= 4095;
        int n = j >> 6, k = j & 63;
        const float* src;
        if (m == 0)      src = lW1 + (size_t)l * 131 * 64;
        else if (m == 1) src = lW1 + (size_t)l * 131 * 64 + 64 * 64;
        else if (m == 2) src = lW2 + (size_t)l * 4096;
        else if (m == 3) src = gW1 + (size_t)l * 4096;
        else             src = gW2 + (size_t)l * 4096;
        WT[i] = f2bf(src[k * 64 + n]);
        return;
    }
    j -= 3 * LYR_SZ;
    if (j < 2048) {
        int n = j >> 6, k = j & 63;
        WT[i] = f2bf(lin1W[k * 32 + n]);
        return;
    }
    j -= 2048;
    {
        int n = j >> 5, k = j & 31;
        WT[i] = (n < 8) ? f2bf(lin2W[k * 8 + n]) : 0;
    }
}

// ---------------------------------------------------------------------------
// bucket build: per-block LDS histogram -> scan -> bucket-grouped packs
// pack = (src<<16) | dst  (both < 2^16)
// ---------------------------------------------------------------------------
__global__ __launch_bounds__(256) void kHist(const int* __restrict__ ei,
                                             int* __restrict__ gHist) {
    __shared__ int h[NB];
    int tid = threadIdx.x;
    for (int i = tid; i < NB; i += 256) h[i] = 0;
    __syncthreads();
    int base = blockIdx.x * HEPB;
#pragma unroll
    for (int k = 0; k < HEPB; k += 256) {
        int e = base + k + tid;
        if (e < N_EDGES) atomicAdd(&h[ei[N_EDGES + e] >> 7], 1);
    }
    __syncthreads();
    for (int i = tid; i < NB; i += 256)
        if (h[i]) atomicAdd(&gHist[i], h[i]);
}

__global__ __launch_bounds__(256) void kScanB(const int* __restrict__ gHist,
                                              int* __restrict__ bucketOff,
                                              int* __restrict__ cursor) {
    __shared__ int s0[512], s1[512];
    int tid = threadIdx.x;
    for (int e = tid; e < 512; e += 256) s0[e] = (e < NB) ? gHist[e] : 0;
    __syncthreads();
    int* sp = s0; int* dp = s1;
    for (int off = 1; off < 512; off <<= 1) {
        for (int e = tid; e < 512; e += 256)
            dp[e] = sp[e] + ((e >= off) ? sp[e - off] : 0);
        __syncthreads();
        int* t = sp; sp = dp; dp = t;
    }
    for (int e = tid; e < NB; e += 256) {
        int excl = sp[e] - gHist[e];
        bucketOff[e] = excl;
        cursor[e] = excl;
    }
    if (tid == 0) bucketOff[NB] = sp[NB - 1];
}

__global__ __launch_bounds__(256) void kScat(const int* __restrict__ ei,
                                             int* __restrict__ cursor,
                                             int* __restrict__ packs) {
    __shared__ int sdata[SEPB];
    __shared__ int hist[NB];
    __shared__ int loff[NB + 1];
    __shared__ int gbase[NB];
    __shared__ int sc0[512], sc1[512];
    int tid = threadIdx.x;
    int base = blockIdx.x * SEPB;
    int nE = min(SEPB, N_EDGES - base);

    for (int i = tid; i < NB; i += 256) hist[i] = 0;
    __syncthreads();

    int myPack[SEPB / 256];
    unsigned short myRank[SEPB / 256];
#pragma unroll
    for (int kk = 0; kk < SEPB / 256; ++kk) {
        int e = base + kk * 256 + tid;
        if (e < N_EDGES) {
            int s = ei[e], d = ei[N_EDGES + e];
            myPack[kk] = (s << 16) | d;
            myRank[kk] = (unsigned short)atomicAdd(&hist[d >> 7], 1);
        }
    }
    __syncthreads();

    for (int e = tid; e < 512; e += 256) sc0[e] = (e < NB) ? hist[e] : 0;
    __syncthreads();
    int* sp = sc0; int* dp = sc1;
    for (int off = 1; off < 512; off <<= 1) {
        for (int e = tid; e < 512; e += 256)
            dp[e] = sp[e] + ((e >= off) ? sp[e - off] : 0);
        __syncthreads();
        int* t = sp; sp = dp; dp = t;
    }
    for (int e = tid; e < NB; e += 256) loff[e] = sp[e] - hist[e];
    if (tid == 0) loff[NB] = sp[NB - 1];
    __syncthreads();

    for (int e = tid; e < NB; e += 256)
        gbase[e] = hist[e] ? atomicAdd(&cursor[e], hist[e]) : 0;
#pragma unroll
    for (int kk = 0; kk < SEPB / 256; ++kk) {
        int e = base + kk * 256 + tid;
        if (e < N_EDGES) {
            int p = myPack[kk];
            int b = (p & 0xffff) >> 7;
            sdata[loff[b] + myRank[kk]] = p;
        }
    }
    __syncthreads();

    for (int i = tid; i < nE; i += 256) {
        int p = sdata[i];
        int b = (p & 0xffff) >> 7;
        packs[gbase[b] + (i - loff[b])] = p;
    }
}

// ---------------------------------------------------------------------------
// per-bucket counting sort -> full per-node CSR (srcList ushort) + rowPtr
// ---------------------------------------------------------------------------
__global__ __launch_bounds__(256) void kSort(
    const int* __restrict__ bucketOff, const int* __restrict__ packs,
    unsigned short* __restrict__ srcList, int* __restrict__ rowPtr) {
    __shared__ int hist[128];
    __shared__ int cur[128];
    __shared__ int sc0[128], sc1[128];
    int tid = threadIdx.x;
    int nbk = blockIdx.x;
    int nodeBase = nbk * 128;
    int nvalid = min(128, N_NODES - nodeBase);
    int eb = bucketOff[nbk], ee = bucketOff[nbk + 1];

    if (tid < 128) hist[tid] = 0;
    __syncthreads();
    for (int i = eb + tid; i < ee; i += 256)
        atomicAdd(&hist[packs[i] & 127], 1);
    __syncthreads();

    if (tid < 128) sc0[tid] = hist[tid];
    __syncthreads();
    int* sp = sc0; int* dp = sc1;
    for (int off = 1; off < 128; off <<= 1) {
        if (tid < 128) dp[tid] = sp[tid] + ((tid >= off) ? sp[tid - off] : 0);
        __syncthreads();
        int* t = sp; sp = dp; dp = t;
    }
    if (tid < 128) {
        int excl = eb + sp[tid] - hist[tid];
        if (tid < nvalid) rowPtr[nodeBase + tid] = excl;
        cur[tid] = excl;
    }
    if (nbk == NB - 1 && tid == 0) rowPtr[N_NODES] = ee;
    __syncthreads();

    for (int i = eb + tid; i < ee; i += 256) {
        int p = packs[i];
        int pos = atomicAdd(&cur[p & 127], 1);
        srcList[pos] = (unsigned short)(((unsigned)p) >> 16);
    }
}

// ---------------------------------------------------------------------------
// aggregation: one wave per node; 16 lanes per edge (ushort4/lane), 4 edges
// in flight per wave, 2-deep unroll => 8 v-row gathers outstanding.
// Channels: lane sub=lane&15 owns ch 4*sub..4*sub+3; quarter q=lane>>4 walks
// edges i = b+q, b+q+4, ... Partial sums combined via shfl_xor(16|32).
// aggH may alias u (u row read before any write; wave owns row n).
// ---------------------------------------------------------------------------
__global__ __launch_bounds__(256) void kAgg(const int* __restrict__ rowPtr,
                                            const unsigned short* __restrict__ srcList,
                                            const unsigned short* __restrict__ u,
                                            const unsigned short* __restrict__ v,
                                            unsigned short* __restrict__ aggH) {
    int gt = blockIdx.x * 256 + threadIdx.x;
    int n = gt >> 6;
    int lane = gt & 63;
    if (n >= N_NODES) return;
    int sub = lane & 15;
    int q = lane >> 4;

    ushort4 uu = *(const ushort4*)(u + (size_t)n * 64 + sub * 4);
    float u0 = bf2f(uu.x), u1 = bf2f(uu.y), u2 = bf2f(uu.z), u3 = bf2f(uu.w);

    int b = rowPtr[n], e = rowPtr[n + 1];
    float a0 = 0.f, a1 = 0.f, a2 = 0.f, a3 = 0.f;
    int i = b + q;
    for (; i + 4 < e; i += 8) {
        int s0 = srcList[i];
        int s1 = srcList[i + 4];
        ushort4 v0 = *(const ushort4*)(v + (size_t)s0 * 64 + sub * 4);
        ushort4 v1 = *(const ushort4*)(v + (size_t)s1 * 64 + sub * 4);
        a0 += fmaxf(u0 + bf2f(v0.x), 0.f) + fmaxf(u0 + bf2f(v1.x), 0.f);
        a1 += fmaxf(u1 + bf2f(v0.y), 0.f) + fmaxf(u1 + bf2f(v1.y), 0.f);
        a2 += fmaxf(u2 + bf2f(v0.z), 0.f) + fmaxf(u2 + bf2f(v1.z), 0.f);
        a3 += fmaxf(u3 + bf2f(v0.w), 0.f) + fmaxf(u3 + bf2f(v1.w), 0.f);
    }
    if (i < e) {
        int s0 = srcList[i];
        ushort4 v0 = *(const ushort4*)(v + (size_t)s0 * 64 + sub * 4);
        a0 += fmaxf(u0 + bf2f(v0.x), 0.f);
        a1 += fmaxf(u1 + bf2f(v0.y), 0.f);
        a2 += fmaxf(u2 + bf2f(v0.z), 0.f);
        a3 += fmaxf(u3 + bf2f(v0.w), 0.f);
    }

    a0 += __shfl_xor(a0, 16); a0 += __shfl_xor(a0, 32);
    a1 += __shfl_xor(a1, 16); a1 += __shfl_xor(a1, 32);
    a2 += __shfl_xor(a2, 16); a2 += __shfl_xor(a2, 32);
    a3 += __shfl_xor(a3, 16); a3 += __shfl_xor(a3, 32);

    if (q == 0) {
        ushort4 o;
        o.x = f2bf(a0); o.y = f2bf(a1); o.z = f2bf(a2); o.w = f2bf(a3);
        *(ushort4*)(aggH + (size_t)n * 64 + sub * 4) = o;
    }
}

// ---------------------------------------------------------------------------
// kA: node_lin (16->64 relu ->64) then u = h@W1a, v = h@W1b + pos@W1c + b1
// ---------------------------------------------------------------------------
__global__ __launch_bounds__(256) void kA(
    const float* __restrict__ x, const float* __restrict__ pos,
    const unsigned short* __restrict__ WT,
    const float* __restrict__ nb1, const float* __restrict__ nb2,
    const float* __restrict__ lW1f, const float* __restrict__ lb1,
    unsigned short* __restrict__ u, unsigned short* __restrict__ v) {
    __shared__ unsigned short Xa[64 * XPITCH];
    __shared__ unsigned short Xb[64 * XPITCH];
    __shared__ float posS[192];
    int tid = threadIdx.x;
    int lane = tid & 63;
    int wv = __builtin_amdgcn_readfirstlane(tid >> 6);
    int nodeBase = blockIdx.x * 64;
    int nvalid = min(64, N_NODES - nodeBase);
    int col = lane & 15;

    for (int idx = tid; idx < 64 * 32; idx += 256) {
        int rowi = idx >> 5, k = idx & 31;
        float val = (k < 16 && rowi < nvalid) ? x[(size_t)(nodeBase + rowi) * 16 + k] : 0.f;
        Xa[rowi * XPITCH + k] = f2bf(val);
    }
    for (int idx = tid; idx < 192; idx += 256)
        posS[idx] = (idx < nvalid * 3) ? pos[(size_t)nodeBase * 3 + idx] : 0.f;
    __syncthreads();

#pragma unroll
    for (int nt = 0; nt < 4; ++nt) {
        f32x4 acc = tile_mm<1, 32>(Xa, WT + OFF_NW1T, wv, nt, lane, mk4(nb1[nt * 16 + col]));
        ep_lds(Xb, wv, nt, lane, acc, true);
    }
    __syncthreads();

#pragma unroll
    for (int nt = 0; nt < 4; ++nt) {
        f32x4 acc = tile_mm<2, 64>(Xb, WT + OFF_NW2T, wv, nt, lane, mk4(nb2[nt * 16 + col]));
        ep_lds(Xa, wv, nt, lane, acc, false);
    }
    __syncthreads();

    const unsigned short* aT = WT + OFF_LYR;
    const unsigned short* bT = aT + 4096;
    const float* W1c = lW1f + 128 * 64;

#pragma unroll
    for (int nt = 0; nt < 4; ++nt) {
        f32x4 acc = tile_mm<2, 64>(Xa, aT, wv, nt, lane, mk4(0.f));
        ep_glob(u, nodeBase, nvalid, wv, nt, lane, acc);
    }
#pragma unroll
    for (int nt = 0; nt < 4; ++nt) {
        int ch = nt * 16 + col;
        f32x4 acc = tile_mm<2, 64>(Xa, bT, wv, nt, lane, mk4(lb1[ch]));
        float w0 = W1c[ch], w1 = W1c[64 + ch], w2 = W1c[128 + ch];
        int quad = lane >> 4;
#pragma unroll
        for (int r = 0; r < 4; ++r) {
            int nl = wv * 16 + quad * 4 + r;
            acc[r] += posS[nl * 3] * w0 + posS[nl * 3 + 1] * w1 + posS[nl * 3 + 2] * w2;
        }
        ep_glob(v, nodeBase, nvalid, wv, nt, lane, acc);
    }
}

// ---------------------------------------------------------------------------
// kB (layers 0,1): aggH -> local_W2/global_nn -> h -> next-layer u,v
// ---------------------------------------------------------------------------
__global__ __launch_bounds__(256) void kB(
    const unsigned short* __restrict__ aggH, const float* __restrict__ pos,
    const int* __restrict__ rowPtr, const unsigned short* __restrict__ WT,
    int l,
    const float* __restrict__ lb2, const float* __restrict__ gb1,
    const float* __restrict__ gb2,
    const float* __restrict__ lW1f_next, const float* __restrict__ b1n,
    unsigned short* __restrict__ u, unsigned short* __restrict__ v) {
    __shared__ unsigned short Xa[64 * XPITCH];
    __shared__ unsigned short Xb[64 * XPITCH];
    __shared__ float posS[192];
    __shared__ float degS[64];
    int tid = threadIdx.x;
    int lane = tid & 63;
    int wv = __builtin_amdgcn_readfirstlane(tid >> 6);
    int nodeBase = blockIdx.x * 64;
    int nvalid = min(64, N_NODES - nodeBase);
    int col = lane & 15;
    int quad = lane >> 4;

    const unsigned short* LYR = WT + OFF_LYR + (size_t)l * LYR_SZ;
    const unsigned short* lW2T = LYR + 2 * 4096;
    const unsigned short* gW1T = LYR + 3 * 4096;
    const unsigned short* gW2T = LYR + 4 * 4096;
    const unsigned short* aTn = WT + OFF_LYR + (size_t)(l + 1) * LYR_SZ;
    const unsigned short* bTn = aTn + 4096;

    const uint4* ag = (const uint4*)(aggH + (size_t)nodeBase * 64);
    for (int idx = tid; idx < 512; idx += 256) {
        int rowi = idx >> 3, seg = idx & 7;
        uint4 d = (rowi < nvalid) ? ag[idx] : make_uint4(0u, 0u, 0u, 0u);
        *(uint4*)&Xa[rowi * XPITCH + seg * 8] = d;
    }
    for (int idx = tid; idx < 192; idx += 256)
        posS[idx] = (idx < nvalid * 3) ? pos[(size_t)nodeBase * 3 + idx] : 0.f;
    if (tid < 64)
        degS[tid] = (tid < nvalid)
            ? (float)(rowPtr[nodeBase + tid + 1] - rowPtr[nodeBase + tid]) : 0.f;
    __syncthreads();

#pragma unroll
    for (int nt = 0; nt < 4; ++nt) {
        float b = lb2[nt * 16 + col];
        f32x4 init;
        float4 dg = *(float4*)&degS[wv * 16 + quad * 4];
        init[0] = dg.x * b; init[1] = dg.y * b; init[2] = dg.z * b; init[3] = dg.w * b;
        f32x4 acc = tile_mm<2, 64>(Xa, lW2T, wv, nt, lane, init);
        ep_lds(Xb, wv, nt, lane, acc, false);
    }
    __syncthreads();

#pragma unroll
    for (int nt = 0; nt < 4; ++nt) {
        f32x4 acc = tile_mm<2, 64>(Xb, gW1T, wv, nt, lane, mk4(gb1[nt * 16 + col]));
        ep_lds(Xa, wv, nt, lane, acc, true);
    }
    __syncthreads();

#pragma unroll
    for (int nt = 0; nt < 4; ++nt) {
        f32x4 acc = tile_mm<2, 64>(Xa, gW2T, wv, nt, lane, mk4(gb2[nt * 16 + col]));
        ep_lds(Xb, wv, nt, lane, acc, true);
    }
    __syncthreads();

#pragma unroll
    for (int nt = 0; nt < 4; ++nt) {
        f32x4 acc = tile_mm<2, 64>(Xb, aTn, wv, nt, lane, mk4(0.f));
        ep_glob(u, nodeBase, nvalid, wv, nt, lane, acc);
    }
    const float* W1c = lW1f_next + 128 * 64;
#pragma unroll
    for (int nt = 0; nt < 4; ++nt) {
        int ch = nt * 16 + col;
        f32x4 acc = tile_mm<2, 64>(Xb, bTn, wv, nt, lane, mk4(b1n[ch]));
        float w0 = W1c[ch], w1 = W1c[64 + ch], w2 = W1c[128 + ch];
#pragma unroll
        for (int r = 0; r < 4; ++r) {
            int nl = wv * 16 + quad * 4 + r;
            acc[r] += posS[nl * 3] * w0 + posS[nl * 3 + 1] * w1 + posS[nl * 3 + 2] * w2;
        }
        ep_glob(v, nodeBase, nvalid, wv, nt, lane, acc);
    }
}

// ---------------------------------------------------------------------------
// kC (layer 2): aggH -> global_nn -> h -> lin1 relu lin2 -> LDS-binned readout
// ---------------------------------------------------------------------------
__global__ __launch_bounds__(256) void kC(
    const unsigned short* __restrict__ aggH, const int* __restrict__ rowPtr,
    const int* __restrict__ batch, const unsigned short* __restrict__ WT,
    const float* __restrict__ lb2, const float* __restrict__ gb1,
    const float* __restrict__ gb2,
    const float* __restrict__ lin1b, const float* __restrict__ lin2b,
    float* __restrict__ out) {
    __shared__ unsigned short Xa[64 * XPITCH];
    __shared__ unsigned short Xb[64 * XPITCH];
    __shared__ float degS[64];
    __shared__ int batchS[64];
    __shared__ float bins[128 * 8];
    int tid = threadIdx.x;
    int lane = tid & 63;
    int wv = __builtin_amdgcn_readfirstlane(tid >> 6);
    int nodeBase = blockIdx.x * 64;
    int nvalid = min(64, N_NODES - nodeBase);
    int col = lane & 15;
    int quad = lane >> 4;

    const unsigned short* LYR = WT + OFF_LYR + 2 * LYR_SZ;
    const unsigned short* lW2T = LYR + 2 * 4096;
    const unsigned short* gW1T = LYR + 3 * 4096;
    const unsigned short* gW2T = LYR + 4 * 4096;
    const unsigned short* lin1T = WT + OFF_LIN1T;
    const unsigned short* lin2T = WT + OFF_LIN2T;

    const uint4* ag = (const uint4*)(aggH + (size_t)nodeBase * 64);
    for (int idx = tid; idx < 512; idx += 256) {
        int rowi = idx >> 3, seg = idx & 7;
        uint4 d = (rowi < nvalid) ? ag[idx] : make_uint4(0u, 0u, 0u, 0u);
        *(uint4*)&Xa[rowi * XPITCH + seg * 8] = d;
    }
    if (tid < 64) {
        degS[tid] = (tid < nvalid)
            ? (float)(rowPtr[nodeBase + tid + 1] - rowPtr[nodeBase + tid]) : 0.f;
        batchS[tid] = (tid < nvalid) ? batch[nodeBase + tid] : batch[N_NODES - 1];
    }
    for (int idx = tid; idx < 128 * 8; idx += 256) bins[idx] = 0.f;
    __syncthreads();

#pragma unroll
    for (int nt = 0; nt < 4; ++nt) {
        float b = lb2[nt * 16 + col];
        f32x4 init;
        float4 dg = *(float4*)&degS[wv * 16 + quad * 4];
        init[0] = dg.x * b; init[1] = dg.y * b; init[2] = dg.z * b; init[3] = dg.w * b;
        f32x4 acc = tile_mm<2, 64>(Xa, lW2T, wv, nt, lane, init);
        ep_lds(Xb, wv, nt, lane, acc, false);
    }
    __syncthreads();
#pragma unroll
    for (int nt = 0; nt < 4; ++nt) {
        f32x4 acc = tile_mm<2, 64>(Xb, gW1T, wv, nt, lane, mk4(gb1[nt * 16 + col]));
        ep_lds(Xa, wv, nt, lane, acc, true);
    }
    __syncthreads();
#pragma unroll
    for (int nt = 0; nt < 4; ++nt) {
        f32x4 acc = tile_mm<2, 64>(Xa, gW2T, wv, nt, lane, mk4(gb2[nt * 16 + col]));
        ep_lds(Xb, wv, nt, lane, acc, true);
    }
    __syncthreads();

#pragma unroll
    for (int nt = 0; nt < 2; ++nt) {
        f32x4 acc = tile_mm<2, 64>(Xb, lin1T, wv, nt, lane, mk4(lin1b[nt * 16 + col]));
        ep_lds(Xa, wv, nt, lane, acc, true);
    }
    __syncthreads();

    {
        f32x4 acc = tile_mm<1, 32>(Xa, lin2T, wv, 0, lane,
                                   mk4(col < 8 ? lin2b[col] : 0.f));
        int gmin = batch[nodeBase];
        if (col < 8) {
#pragma unroll
            for (int r = 0; r < 4; ++r) {
                int nl = wv * 16 + quad * 4 + r;
                if (nl < nvalid)
                    atomicAdd(&bins[(batchS[nl] - gmin) * 8 + col], acc[r]);
            }
        }
        __syncthreads();
        int nb8 = (batchS[nvalid - 1] - gmin + 1) * 8;
        for (int idx = tid; idx < nb8; idx += 256)
            atomAddF(&out[gmin * 8 + idx], bins[idx]);
    }
}

// ---------------------------------------------------------------------------
// launch
// ---------------------------------------------------------------------------
extern "C" void kernel_launch(void* const* d_in, const int* in_sizes, int n_in,
                              void* d_out, int out_size, void* d_ws, size_t ws_size,
                              hipStream_t stream) {
    const float* x     = (const float*)d_in[0];
    const float* pos   = (const float*)d_in[1];
    const int*   ei    = (const int*)d_in[2];
    const int*   batch = (const int*)d_in[3];
    const float* nW1   = (const float*)d_in[4];
    const float* nb1   = (const float*)d_in[5];
    const float* nW2   = (const float*)d_in[6];
    const float* nb2   = (const float*)d_in[7];
    const float* lW1   = (const float*)d_in[8];
    const float* lb1   = (const float*)d_in[9];
    const float* lW2   = (const float*)d_in[10];
    const float* lb2   = (const float*)d_in[11];
    const float* gW1   = (const float*)d_in[12];
    const float* gb1   = (const float*)d_in[13];
    const float* gW2   = (const float*)d_in[14];
    const float* gb2   = (const float*)d_in[15];
    const float* lin1W = (const float*)d_in[16];
    const float* lin1b = (const float*)d_in[17];
    const float* lin2W = (const float*)d_in[18];
    const float* lin2b = (const float*)d_in[19];
    float* out = (float*)d_out;

    // workspace (u doubles as aggH)
    unsigned short* u  = (unsigned short*)d_ws;          // N*64 bf16
    unsigned short* v  = u + (size_t)N_NODES * 64;       // N*64 bf16
    unsigned short* WT = v + (size_t)N_NODES * 64;       // WT_TOTAL bf16
    int* gHist = (int*)(WT + WT_TOTAL);                  // NB
    int* bucketOff = gHist + NB;                         // NB+1
    int* cursor = bucketOff + NB + 1;                    // NB
    int* rowPtr = cursor + NB;                           // N+1
    int* packs = rowPtr + N_NODES + 1;                   // E int
    unsigned short* srcList = (unsigned short*)(packs + N_EDGES); // E ushort
    unsigned short* aggH = u;

    const int nodeBlocks = (N_NODES + 63) / 64;
    const int aggBlocks  = (N_NODES * 64 + 255) / 256;

    hipMemsetAsync(gHist, 0, NB * sizeof(int), stream);
    hipMemsetAsync(out, 0, (size_t)out_size * sizeof(float), stream);

    kPrep<<<(WT_TOTAL + 255) / 256, 256, 0, stream>>>(nW1, nW2, lW1, lW2, gW1, gW2,
                                                      lin1W, lin2W, WT);
    kHist<<<(N_EDGES + HEPB - 1) / HEPB, 256, 0, stream>>>(ei, gHist);
    kScanB<<<1, 256, 0, stream>>>(gHist, bucketOff, cursor);
    kScat<<<(N_EDGES + SEPB - 1) / SEPB, 256, 0, stream>>>(ei, cursor, packs);
    kSort<<<NB, 256, 0, stream>>>(bucketOff, packs, srcList, rowPtr);

    kA<<<nodeBlocks, 256, 0, stream>>>(x, pos, WT, nb1, nb2, lW1, lb1, u, v);

    for (int l = 0; l < 3; ++l) {
        kAgg<<<aggBlocks, 256, 0, stream>>>(rowPtr, srcList, u, v, aggH);
        if (l < 2) {
            kB<<<nodeBlocks, 256, 0, stream>>>(
                aggH, pos, rowPtr, WT, l,
                lb2 + l * 64, gb1 + l * 64, gb2 + l * 64,
                lW1 + (size_t)(l + 1) * 131 * 64, lb1 + (l + 1) * 64,
                u, v);
        } else {
            kC<<<nodeBlocks, 256, 0, stream>>>(
                aggH, rowPtr, batch, WT,
                lb2 + l * 64, gb1 + l * 64, gb2 + l * 64,
                lin1b, lin2b, out);
        }
    }
}

// Round 8
// 305.146 us; speedup vs baseline: 4.3215x; 1.0210x over previous
//
#include <hip/hip_runtime.h>

#define N_NODES 50000
#define N_EDGES 800000
#define NGRAPH  128
#define XPITCH  72   // ushort pitch: 72*2=144B, 16B-aligned rows, 2-way (free) banks
#define NB      391  // dst buckets of 128 nodes
#define HEPB    4096
#define SEPB    8192

typedef short bf16x8 __attribute__((ext_vector_type(8)));
typedef float f32x4  __attribute__((ext_vector_type(4)));

// ---------------------------------------------------------------------------
// helpers
// ---------------------------------------------------------------------------

__device__ __forceinline__ float atomAddF(float* p, float v) {
#if defined(__gfx950__) || defined(__AMDGCN__)
    return unsafeAtomicAdd(p, v);
#else
    return atomicAdd(p, v);
#endif
}

__device__ __forceinline__ unsigned short f2bf(float x) {  // RNE f32 -> bf16
    unsigned u = __builtin_bit_cast(unsigned, x);
    u += 0x7fffu + ((u >> 16) & 1u);
    return (unsigned short)(u >> 16);
}
__device__ __forceinline__ float bf2f(unsigned short h) {
    return __builtin_bit_cast(float, (unsigned)h << 16);
}

__device__ __forceinline__ f32x4 mk4(float b) { f32x4 a = {b, b, b, b}; return a; }

// One 16x16 tile vs weight mat, A-frags preloaded in regs.
template<int NKC, int KROW>
__device__ __forceinline__ f32x4 w_tile(const bf16x8* a,
                                        const unsigned short* __restrict__ Wm,
                                        int nt, int col, int quad, f32x4 acc) {
    const unsigned short* wp = Wm + (nt * 16 + col) * KROW + quad * 8;
#pragma unroll
    for (int c = 0; c < NKC; ++c) {
        bf16x8 b = *(const bf16x8*)(wp + c * 32);
        acc = __builtin_amdgcn_mfma_f32_16x16x32_bf16(a[c], b, acc, 0, 0, 0);
    }
    return acc;
}

// load A-frags (wave-private slice, rows = local m, m=col)
template<int NKC>
__device__ __forceinline__ void a_load(const unsigned short* __restrict__ sl,
                                       int col, int quad, bf16x8* a) {
    a[0] = *(const bf16x8*)(sl + col * XPITCH + quad * 8);
    if (NKC > 1) a[1] = *(const bf16x8*)(sl + col * XPITCH + quad * 8 + 32);
}

// write NNT n-tiles back into wave slice (in place; all A reads already done)
template<int NNT>
__device__ __forceinline__ void w_store(unsigned short* __restrict__ sl,
                                        int col, int quad, const f32x4* acc4,
                                        bool relu) {
#pragma unroll
    for (int nt = 0; nt < NNT; ++nt)
#pragma unroll
        for (int r = 0; r < 4; ++r) {
            float x = acc4[nt][r];
            if (relu) x = fmaxf(x, 0.f);
            sl[(quad * 4 + r) * XPITCH + nt * 16 + col] = f2bf(x);
        }
}

// store 4 n-tiles to global rows (node-major bf16[64])
__device__ __forceinline__ void g_store(unsigned short* __restrict__ g, int gn0,
                                        int col, int quad, const f32x4* acc4) {
#pragma unroll
    for (int nt = 0; nt < 4; ++nt)
#pragma unroll
        for (int r = 0; r < 4; ++r) {
            int node = gn0 + quad * 4 + r;
            if (node < N_NODES)
                g[(size_t)node * 64 + nt * 16 + col] = f2bf(acc4[nt][r]);
        }
}

// ---------------------------------------------------------------------------
// weight prep (transpose + bf16 into B-operand layout); also zeroes gHist/out
// ---------------------------------------------------------------------------
#define OFF_NW1T  0
#define OFF_NW2T  2048
#define OFF_LYR   6144
#define LYR_SZ    20480
#define OFF_LIN1T 67584
#define OFF_LIN2T 69632
#define WT_TOTAL  70144

__global__ __launch_bounds__(256) void kPrep(
    const float* __restrict__ nW1, const float* __restrict__ nW2,
    const float* __restrict__ lW1, const float* __restrict__ lW2,
    const float* __restrict__ gW1, const float* __restrict__ gW2,
    const float* __restrict__ lin1W, const float* __restrict__ lin2W,
    unsigned short* __restrict__ WT, int* __restrict__ gHist,
    float* __restrict__ out) {
    int i = blockIdx.x * 256 + threadIdx.x;
    if (blockIdx.x == 0) {
        for (int k = threadIdx.x; k < NB; k += 256) gHist[k] = 0;
        for (int k = threadIdx.x; k < NGRAPH * 8; k += 256) out[k] = 0.f;
    }
    if (i >= WT_TOTAL) return;
    int j = i;
    if (j < 2048) {
        int n = j >> 5, k = j & 31;
        WT[i] = (k < 16) ? f2bf(nW1[k * 64 + n]) : 0;
        return;
    }
    j -= 2048;
    if (j < 4096) {
        int n = j >> 6, k = j & 63;
        WT[i] = f2bf(nW2[k * 64 + n]);
        return;
    }
    j -= 4096;
    if (j < 3 * LYR_SZ) {
        int l = j / LYR_SZ;  j -= l * LYR_SZ;
        int m = j >> 12;     j &= 4095;
        int n = j >> 6, k = j & 63;
        const float* src;
        if (m == 0)      src = lW1 + (size_t)l * 131 * 64;
        else if (m == 1) src = lW1 + (size_t)l * 131 * 64 + 64 * 64;
        else if (m == 2) src = lW2 + (size_t)l * 4096;
        else if (m == 3) src = gW1 + (size_t)l * 4096;
        else             src = gW2 + (size_t)l * 4096;
        WT[i] = f2bf(src[k * 64 + n]);
        return;
    }
    j -= 3 * LYR_SZ;
    if (j < 2048) {
        int n = j >> 6, k = j & 63;
        WT[i] = f2bf(lin1W[k * 32 + n]);
        return;
    }
    j -= 2048;
    {
        int n = j >> 5, k = j & 31;
        WT[i] = (n < 8) ? f2bf(lin2W[k * 8 + n]) : 0;
    }
}

// ---------------------------------------------------------------------------
// bucket build (unchanged from R7): hist -> scan -> bucket scatter -> sort
// ---------------------------------------------------------------------------
__global__ __launch_bounds__(256) void kHist(const int* __restrict__ ei,
                                             int* __restrict__ gHist) {
    __shared__ int h[NB];
    int tid = threadIdx.x;
    for (int i = tid; i < NB; i += 256) h[i] = 0;
    __syncthreads();
    int base = blockIdx.x * HEPB;
#pragma unroll
    for (int k = 0; k < HEPB; k += 256) {
        int e = base + k + tid;
        if (e < N_EDGES) atomicAdd(&h[ei[N_EDGES + e] >> 7], 1);
    }
    __syncthreads();
    for (int i = tid; i < NB; i += 256)
        if (h[i]) atomicAdd(&gHist[i], h[i]);
}

__global__ __launch_bounds__(256) void kScanB(const int* __restrict__ gHist,
                                              int* __restrict__ bucketOff,
                                              int* __restrict__ cursor) {
    __shared__ int s0[512], s1[512];
    int tid = threadIdx.x;
    for (int e = tid; e < 512; e += 256) s0[e] = (e < NB) ? gHist[e] : 0;
    __syncthreads();
    int* sp = s0; int* dp = s1;
    for (int off = 1; off < 512; off <<= 1) {
        for (int e = tid; e < 512; e += 256)
            dp[e] = sp[e] + ((e >= off) ? sp[e - off] : 0);
        __syncthreads();
        int* t = sp; sp = dp; dp = t;
    }
    for (int e = tid; e < NB; e += 256) {
        int excl = sp[e] - gHist[e];
        bucketOff[e] = excl;
        cursor[e] = excl;
    }
    if (tid == 0) bucketOff[NB] = sp[NB - 1];
}

__global__ __launch_bounds__(256) void kScat(const int* __restrict__ ei,
                                             int* __restrict__ cursor,
                                             int* __restrict__ packs) {
    __shared__ int sdata[SEPB];
    __shared__ int hist[NB];
    __shared__ int loff[NB + 1];
    __shared__ int gbase[NB];
    __shared__ int sc0[512], sc1[512];
    int tid = threadIdx.x;
    int base = blockIdx.x * SEPB;
    int nE = min(SEPB, N_EDGES - base);

    for (int i = tid; i < NB; i += 256) hist[i] = 0;
    __syncthreads();

    int myPack[SEPB / 256];
    unsigned short myRank[SEPB / 256];
#pragma unroll
    for (int kk = 0; kk < SEPB / 256; ++kk) {
        int e = base + kk * 256 + tid;
        if (e < N_EDGES) {
            int s = ei[e], d = ei[N_EDGES + e];
            myPack[kk] = (s << 16) | d;
            myRank[kk] = (unsigned short)atomicAdd(&hist[d >> 7], 1);
        }
    }
    __syncthreads();

    for (int e = tid; e < 512; e += 256) sc0[e] = (e < NB) ? hist[e] : 0;
    __syncthreads();
    int* sp = sc0; int* dp = sc1;
    for (int off = 1; off < 512; off <<= 1) {
        for (int e = tid; e < 512; e += 256)
            dp[e] = sp[e] + ((e >= off) ? sp[e - off] : 0);
        __syncthreads();
        int* t = sp; sp = dp; dp = t;
    }
    for (int e = tid; e < NB; e += 256) loff[e] = sp[e] - hist[e];
    if (tid == 0) loff[NB] = sp[NB - 1];
    __syncthreads();

    for (int e = tid; e < NB; e += 256)
        gbase[e] = hist[e] ? atomicAdd(&cursor[e], hist[e]) : 0;
#pragma unroll
    for (int kk = 0; kk < SEPB / 256; ++kk) {
        int e = base + kk * 256 + tid;
        if (e < N_EDGES) {
            int p = myPack[kk];
            int b = (p & 0xffff) >> 7;
            sdata[loff[b] + myRank[kk]] = p;
        }
    }
    __syncthreads();

    for (int i = tid; i < nE; i += 256) {
        int p = sdata[i];
        int b = (p & 0xffff) >> 7;
        packs[gbase[b] + (i - loff[b])] = p;
    }
}

__global__ __launch_bounds__(256) void kSort(
    const int* __restrict__ bucketOff, const int* __restrict__ packs,
    unsigned short* __restrict__ srcList, int* __restrict__ rowPtr) {
    __shared__ int hist[128];
    __shared__ int cur[128];
    __shared__ int sc0[128], sc1[128];
    int tid = threadIdx.x;
    int nbk = blockIdx.x;
    int nodeBase = nbk * 128;
    int nvalid = min(128, N_NODES - nodeBase);
    int eb = bucketOff[nbk], ee = bucketOff[nbk + 1];

    if (tid < 128) hist[tid] = 0;
    __syncthreads();
    for (int i = eb + tid; i < ee; i += 256)
        atomicAdd(&hist[packs[i] & 127], 1);
    __syncthreads();

    if (tid < 128) sc0[tid] = hist[tid];
    __syncthreads();
    int* sp = sc0; int* dp = sc1;
    for (int off = 1; off < 128; off <<= 1) {
        if (tid < 128) dp[tid] = sp[tid] + ((tid >= off) ? sp[tid - off] : 0);
        __syncthreads();
        int* t = sp; sp = dp; dp = t;
    }
    if (tid < 128) {
        int excl = eb + sp[tid] - hist[tid];
        if (tid < nvalid) rowPtr[nodeBase + tid] = excl;
        cur[tid] = excl;
    }
    if (nbk == NB - 1 && tid == 0) rowPtr[N_NODES] = ee;
    __syncthreads();

    for (int i = eb + tid; i < ee; i += 256) {
        int p = packs[i];
        int pos = atomicAdd(&cur[p & 127], 1);
        srcList[pos] = (unsigned short)(((unsigned)p) >> 16);
    }
}

// ---------------------------------------------------------------------------
// aggregation (unchanged from R7): wave/node, 16 lanes/edge, shfl reduce
// ---------------------------------------------------------------------------
__global__ __launch_bounds__(256) void kAgg(const int* __restrict__ rowPtr,
                                            const unsigned short* __restrict__ srcList,
                                            const unsigned short* __restrict__ u,
                                            const unsigned short* __restrict__ v,
                                            unsigned short* __restrict__ aggH) {
    int gt = blockIdx.x * 256 + threadIdx.x;
    int n = gt >> 6;
    int lane = gt & 63;
    if (n >= N_NODES) return;
    int sub = lane & 15;
    int q = lane >> 4;

    ushort4 uu = *(const ushort4*)(u + (size_t)n * 64 + sub * 4);
    float u0 = bf2f(uu.x), u1 = bf2f(uu.y), u2 = bf2f(uu.z), u3 = bf2f(uu.w);

    int b = rowPtr[n], e = rowPtr[n + 1];
    float a0 = 0.f, a1 = 0.f, a2 = 0.f, a3 = 0.f;
    int i = b + q;
    for (; i + 4 < e; i += 8) {
        int s0 = srcList[i];
        int s1 = srcList[i + 4];
        ushort4 v0 = *(const ushort4*)(v + (size_t)s0 * 64 + sub * 4);
        ushort4 v1 = *(const ushort4*)(v + (size_t)s1 * 64 + sub * 4);
        a0 += fmaxf(u0 + bf2f(v0.x), 0.f) + fmaxf(u0 + bf2f(v1.x), 0.f);
        a1 += fmaxf(u1 + bf2f(v0.y), 0.f) + fmaxf(u1 + bf2f(v1.y), 0.f);
        a2 += fmaxf(u2 + bf2f(v0.z), 0.f) + fmaxf(u2 + bf2f(v1.z), 0.f);
        a3 += fmaxf(u3 + bf2f(v0.w), 0.f) + fmaxf(u3 + bf2f(v1.w), 0.f);
    }
    if (i < e) {
        int s0 = srcList[i];
        ushort4 v0 = *(const ushort4*)(v + (size_t)s0 * 64 + sub * 4);
        a0 += fmaxf(u0 + bf2f(v0.x), 0.f);
        a1 += fmaxf(u1 + bf2f(v0.y), 0.f);
        a2 += fmaxf(u2 + bf2f(v0.z), 0.f);
        a3 += fmaxf(u3 + bf2f(v0.w), 0.f);
    }

    a0 += __shfl_xor(a0, 16); a0 += __shfl_xor(a0, 32);
    a1 += __shfl_xor(a1, 16); a1 += __shfl_xor(a1, 32);
    a2 += __shfl_xor(a2, 16); a2 += __shfl_xor(a2, 32);
    a3 += __shfl_xor(a3, 16); a3 += __shfl_xor(a3, 32);

    if (q == 0) {
        ushort4 o;
        o.x = f2bf(a0); o.y = f2bf(a1); o.z = f2bf(a2); o.w = f2bf(a3);
        *(ushort4*)(aggH + (size_t)n * 64 + sub * 4) = o;
    }
}

// ---------------------------------------------------------------------------
// kA: barrier-free. Each wave owns 16 nodes; private LDS slice; stages chain
// in place (A-frags in regs before writeback, lgkmcnt ordering only).
// ---------------------------------------------------------------------------
__global__ __launch_bounds__(256) void kA(
    const float* __restrict__ x, const float* __restrict__ pos,
    const unsigned short* __restrict__ WT,
    const float* __restrict__ nb1, const float* __restrict__ nb2,
    const float* __restrict__ lW1f, const float* __restrict__ lb1,
    unsigned short* __restrict__ u, unsigned short* __restrict__ v) {
    __shared__ unsigned short SL[4 * 16 * XPITCH];
    __shared__ float posW[4 * 48];
    int tid = threadIdx.x;
    int lane = tid & 63;
    int wv = __builtin_amdgcn_readfirstlane(tid >> 6);
    unsigned short* sl = SL + wv * 16 * XPITCH;
    float* pw = posW + wv * 48;
    int gn0 = blockIdx.x * 64 + wv * 16;
    int col = lane & 15, quad = lane >> 4;

    // wave-private staging: x rows (k 0..15), zeros k 16..31; pos
    for (int idx = lane; idx < 512; idx += 64) {
        int m = idx >> 5, k = idx & 31;
        int node = gn0 + m;
        float val = (k < 16 && node < N_NODES) ? x[(size_t)node * 16 + k] : 0.f;
        sl[m * XPITCH + k] = f2bf(val);
    }
    for (int idx = lane; idx < 48; idx += 64) {
        int node = gn0 + idx / 3;
        pw[idx] = (node < N_NODES) ? pos[(size_t)node * 3 + idx % 3] : 0.f;
    }

    bf16x8 a[2];
    f32x4 acc4[4];

    // s1: relu(x @ nW1 + nb1)
    a_load<1>(sl, col, quad, a);
#pragma unroll
    for (int nt = 0; nt < 4; ++nt)
        acc4[nt] = w_tile<1, 32>(a, WT + OFF_NW1T, nt, col, quad, mk4(nb1[nt * 16 + col]));
    w_store<4>(sl, col, quad, acc4, true);

    // s2: h = @nW2 + nb2
    a_load<2>(sl, col, quad, a);
#pragma unroll
    for (int nt = 0; nt < 4; ++nt)
        acc4[nt] = w_tile<2, 64>(a, WT + OFF_NW2T, nt, col, quad, mk4(nb2[nt * 16 + col]));
    w_store<4>(sl, col, quad, acc4, false);

    const unsigned short* aT = WT + OFF_LYR;
    const unsigned short* bT = aT + 4096;
    const float* W1c = lW1f + 128 * 64;

    // s3: u = h @ aT (slice untouched)
    a_load<2>(sl, col, quad, a);
#pragma unroll
    for (int nt = 0; nt < 4; ++nt)
        acc4[nt] = w_tile<2, 64>(a, aT, nt, col, quad, mk4(0.f));
    g_store(u, gn0, col, quad, acc4);

    // s4: v = h @ bT + pos @ W1c + lb1
    float px[4], py[4], pz[4];
#pragma unroll
    for (int r = 0; r < 4; ++r) {
        px[r] = pw[(quad * 4 + r) * 3 + 0];
        py[r] = pw[(quad * 4 + r) * 3 + 1];
        pz[r] = pw[(quad * 4 + r) * 3 + 2];
    }
#pragma unroll
    for (int nt = 0; nt < 4; ++nt) {
        int ch = nt * 16 + col;
        acc4[nt] = w_tile<2, 64>(a, bT, nt, col, quad, mk4(lb1[ch]));
        float w0 = W1c[ch], w1 = W1c[64 + ch], w2 = W1c[128 + ch];
#pragma unroll
        for (int r = 0; r < 4; ++r)
            acc4[nt][r] += px[r] * w0 + py[r] * w1 + pz[r] * w2;
    }
    g_store(v, gn0, col, quad, acc4);
}

// ---------------------------------------------------------------------------
// kB (layers 0,1): barrier-free wave pipelines
// ---------------------------------------------------------------------------
__global__ __launch_bounds__(256) void kB(
    const unsigned short* __restrict__ aggH, const float* __restrict__ pos,
    const int* __restrict__ rowPtr, const unsigned short* __restrict__ WT,
    int l,
    const float* __restrict__ lb2, const float* __restrict__ gb1,
    const float* __restrict__ gb2,
    const float* __restrict__ lW1f_next, const float* __restrict__ b1n,
    unsigned short* __restrict__ u, unsigned short* __restrict__ v) {
    __shared__ unsigned short SL[4 * 16 * XPITCH];
    __shared__ float posW[4 * 48];
    __shared__ float degW[4 * 16];
    int tid = threadIdx.x;
    int lane = tid & 63;
    int wv = __builtin_amdgcn_readfirstlane(tid >> 6);
    unsigned short* sl = SL + wv * 16 * XPITCH;
    float* pw = posW + wv * 48;
    float* dw = degW + wv * 16;
    int gn0 = blockIdx.x * 64 + wv * 16;
    int col = lane & 15, quad = lane >> 4;

    const unsigned short* LYR = WT + OFF_LYR + (size_t)l * LYR_SZ;
    const unsigned short* lW2T = LYR + 2 * 4096;
    const unsigned short* gW1T = LYR + 3 * 4096;
    const unsigned short* gW2T = LYR + 4 * 4096;
    const unsigned short* aTn = WT + OFF_LYR + (size_t)(l + 1) * LYR_SZ;
    const unsigned short* bTn = aTn + 4096;

    // wave-private staging: aggH rows, pos, deg
    const uint4* ag = (const uint4*)(aggH + (size_t)gn0 * 64);
    for (int idx = lane; idx < 128; idx += 64) {
        int m = idx >> 3, seg = idx & 7;
        uint4 d = (gn0 + m < N_NODES) ? ag[idx] : make_uint4(0u, 0u, 0u, 0u);
        *(uint4*)&sl[m * XPITCH + seg * 8] = d;
    }
    for (int idx = lane; idx < 48; idx += 64) {
        int node = gn0 + idx / 3;
        pw[idx] = (node < N_NODES) ? pos[(size_t)node * 3 + idx % 3] : 0.f;
    }
    if (lane < 16) {
        int node = min(gn0 + lane, N_NODES - 1);
        dw[lane] = (float)(rowPtr[node + 1] - rowPtr[node]);
    }

    bf16x8 a[2];
    f32x4 acc4[4];
    float dgr[4];
#pragma unroll
    for (int r = 0; r < 4; ++r) dgr[r] = dw[quad * 4 + r];

    // s1: agg = aggH @ lW2 + deg*lb2
    a_load<2>(sl, col, quad, a);
#pragma unroll
    for (int nt = 0; nt < 4; ++nt) {
        float b = lb2[nt * 16 + col];
        f32x4 init = {dgr[0] * b, dgr[1] * b, dgr[2] * b, dgr[3] * b};
        acc4[nt] = w_tile<2, 64>(a, lW2T, nt, col, quad, init);
    }
    w_store<4>(sl, col, quad, acc4, false);

    // s2: relu(@gW1 + gb1)
    a_load<2>(sl, col, quad, a);
#pragma unroll
    for (int nt = 0; nt < 4; ++nt)
        acc4[nt] = w_tile<2, 64>(a, gW1T, nt, col, quad, mk4(gb1[nt * 16 + col]));
    w_store<4>(sl, col, quad, acc4, true);

    // s3: h = relu(@gW2 + gb2)
    a_load<2>(sl, col, quad, a);
#pragma unroll
    for (int nt = 0; nt < 4; ++nt)
        acc4[nt] = w_tile<2, 64>(a, gW2T, nt, col, quad, mk4(gb2[nt * 16 + col]));
    w_store<4>(sl, col, quad, acc4, true);

    // s4: u = h @ aT(next)
    a_load<2>(sl, col, quad, a);
#pragma unroll
    for (int nt = 0; nt < 4; ++nt)
        acc4[nt] = w_tile<2, 64>(a, aTn, nt, col, quad, mk4(0.f));
    g_store(u, gn0, col, quad, acc4);

    // s5: v = h @ bT(next) + pos @ W1c(next) + b1(next)
    const float* W1c = lW1f_next + 128 * 64;
    float px[4], py[4], pz[4];
#pragma unroll
    for (int r = 0; r < 4; ++r) {
        px[r] = pw[(quad * 4 + r) * 3 + 0];
        py[r] = pw[(quad * 4 + r) * 3 + 1];
        pz[r] = pw[(quad * 4 + r) * 3 + 2];
    }
#pragma unroll
    for (int nt = 0; nt < 4; ++nt) {
        int ch = nt * 16 + col;
        acc4[nt] = w_tile<2, 64>(a, bTn, nt, col, quad, mk4(b1n[ch]));
        float w0 = W1c[ch], w1 = W1c[64 + ch], w2 = W1c[128 + ch];
#pragma unroll
        for (int r = 0; r < 4; ++r)
            acc4[nt][r] += px[r] * w0 + py[r] * w1 + pz[r] * w2;
    }
    g_store(v, gn0, col, quad, acc4);
}

// ---------------------------------------------------------------------------
// kC (layer 2): wave pipelines + block-shared readout bins (2 barriers total)
// ---------------------------------------------------------------------------
__global__ __launch_bounds__(256) void kC(
    const unsigned short* __restrict__ aggH, const int* __restrict__ rowPtr,
    const int* __restrict__ batch, const unsigned short* __restrict__ WT,
    const float* __restrict__ lb2, const float* __restrict__ gb1,
    const float* __restrict__ gb2,
    const float* __restrict__ lin1b, const float* __restrict__ lin2b,
    float* __restrict__ out) {
    __shared__ unsigned short SL[4 * 16 * XPITCH];
    __shared__ float degW[4 * 16];
    __shared__ int batchW[64];
    __shared__ float bins[128 * 8];
    int tid = threadIdx.x;
    int lane = tid & 63;
    int wv = __builtin_amdgcn_readfirstlane(tid >> 6);
    unsigned short* sl = SL + wv * 16 * XPITCH;
    float* dw = degW + wv * 16;
    int nodeBase = blockIdx.x * 64;
    int gn0 = nodeBase + wv * 16;
    int nvalid = min(64, N_NODES - nodeBase);
    int col = lane & 15, quad = lane >> 4;

    const unsigned short* LYR = WT + OFF_LYR + 2 * LYR_SZ;
    const unsigned short* lW2T = LYR + 2 * 4096;
    const unsigned short* gW1T = LYR + 3 * 4096;
    const unsigned short* gW2T = LYR + 4 * 4096;
    const unsigned short* lin1T = WT + OFF_LIN1T;
    const unsigned short* lin2T = WT + OFF_LIN2T;

    for (int idx = tid; idx < 128 * 8; idx += 256) bins[idx] = 0.f;
    const uint4* ag = (const uint4*)(aggH + (size_t)gn0 * 64);
    for (int idx = lane; idx < 128; idx += 64) {
        int m = idx >> 3, seg = idx & 7;
        uint4 d = (gn0 + m < N_NODES) ? ag[idx] : make_uint4(0u, 0u, 0u, 0u);
        *(uint4*)&sl[m * XPITCH + seg * 8] = d;
    }
    if (lane < 16) {
        int node = min(gn0 + lane, N_NODES - 1);
        dw[lane] = (float)(rowPtr[node + 1] - rowPtr[node]);
        batchW[wv * 16 + lane] = batch[node];
    }
    __syncthreads();   // bins zero + batchW visible before any atomic add

    bf16x8 a[2];
    f32x4 acc4[4];
    float dgr[4];
#pragma unroll
    for (int r = 0; r < 4; ++r) dgr[r] = dw[quad * 4 + r];

    a_load<2>(sl, col, quad, a);
#pragma unroll
    for (int nt = 0; nt < 4; ++nt) {
        float b = lb2[nt * 16 + col];
        f32x4 init = {dgr[0] * b, dgr[1] * b, dgr[2] * b, dgr[3] * b};
        acc4[nt] = w_tile<2, 64>(a, lW2T, nt, col, quad, init);
    }
    w_store<4>(sl, col, quad, acc4, false);

    a_load<2>(sl, col, quad, a);
#pragma unroll
    for (int nt = 0; nt < 4; ++nt)
        acc4[nt] = w_tile<2, 64>(a, gW1T, nt, col, quad, mk4(gb1[nt * 16 + col]));
    w_store<4>(sl, col, quad, acc4, true);

    a_load<2>(sl, col, quad, a);
#pragma unroll
    for (int nt = 0; nt < 4; ++nt)
        acc4[nt] = w_tile<2, 64>(a, gW2T, nt, col, quad, mk4(gb2[nt * 16 + col]));
    w_store<4>(sl, col, quad, acc4, true);

    // lin1: 64 -> 32 (2 n-tiles)
    a_load<2>(sl, col, quad, a);
#pragma unroll
    for (int nt = 0; nt < 2; ++nt)
        acc4[nt] = w_tile<2, 64>(a, lin1T, nt, col, quad, mk4(lin1b[nt * 16 + col]));
    w_store<2>(sl, col, quad, acc4, true);

    // lin2: 32 -> 8
    a_load<1>(sl, col, quad, a);
    f32x4 o = w_tile<1, 32>(a, lin2T, 0, col, quad,
                            mk4(col < 8 ? lin2b[col] : 0.f));

    int gmin = batch[nodeBase];
    if (col < 8) {
#pragma unroll
        for (int r = 0; r < 4; ++r) {
            int nl = wv * 16 + quad * 4 + r;
            if (nl < nvalid)
                atomicAdd(&bins[(batchW[nl] - gmin) * 8 + col], o[r]);
        }
    }
    __syncthreads();
    int gmax = batch[nodeBase + nvalid - 1];
    int nb8 = (gmax - gmin + 1) * 8;
    for (int idx = tid; idx < nb8; idx += 256)
        atomAddF(&out[gmin * 8 + idx], bins[idx]);
}

// ---------------------------------------------------------------------------
// launch
// ---------------------------------------------------------------------------
extern "C" void kernel_launch(void* const* d_in, const int* in_sizes, int n_in,
                              void* d_out, int out_size, void* d_ws, size_t ws_size,
                              hipStream_t stream) {
    const float* x     = (const float*)d_in[0];
    const float* pos   = (const float*)d_in[1];
    const int*   ei    = (const int*)d_in[2];
    const int*   batch = (const int*)d_in[3];
    const float* nW1   = (const float*)d_in[4];
    const float* nb1   = (const float*)d_in[5];
    const float* nW2   = (const float*)d_in[6];
    const float* nb2   = (const float*)d_in[7];
    const float* lW1   = (const float*)d_in[8];
    const float* lb1   = (const float*)d_in[9];
    const float* lW2   = (const float*)d_in[10];
    const float* lb2   = (const float*)d_in[11];
    const float* gW1   = (const float*)d_in[12];
    const float* gb1   = (const float*)d_in[13];
    const float* gW2   = (const float*)d_in[14];
    const float* gb2   = (const float*)d_in[15];
    const float* lin1W = (const float*)d_in[16];
    const float* lin1b = (const float*)d_in[17];
    const float* lin2W = (const float*)d_in[18];
    const float* lin2b = (const float*)d_in[19];
    float* out = (float*)d_out;

    // workspace (u doubles as aggH)
    unsigned short* u  = (unsigned short*)d_ws;          // N*64 bf16
    unsigned short* v  = u + (size_t)N_NODES * 64;       // N*64 bf16
    unsigned short* WT = v + (size_t)N_NODES * 64;       // WT_TOTAL bf16
    int* gHist = (int*)(WT + WT_TOTAL);                  // NB
    int* bucketOff = gHist + NB;                         // NB+1
    int* cursor = bucketOff + NB + 1;                    // NB
    int* rowPtr = cursor + NB;                           // N+1
    int* packs = rowPtr + N_NODES + 1;                   // E int
    unsigned short* srcList = (unsigned short*)(packs + N_EDGES); // E ushort
    unsigned short* aggH = u;

    const int nodeBlocks = (N_NODES + 63) / 64;
    const int aggBlocks  = (N_NODES * 64 + 255) / 256;

    kPrep<<<(WT_TOTAL + 255) / 256, 256, 0, stream>>>(nW1, nW2, lW1, lW2, gW1, gW2,
                                                      lin1W, lin2W, WT, gHist, out);
    kHist<<<(N_EDGES + HEPB - 1) / HEPB, 256, 0, stream>>>(ei, gHist);
    kScanB<<<1, 256, 0, stream>>>(gHist, bucketOff, cursor);
    kScat<<<(N_EDGES + SEPB - 1) / SEPB, 256, 0, stream>>>(ei, cursor, packs);
    kSort<<<NB, 256, 0, stream>>>(bucketOff, packs, srcList, rowPtr);

    kA<<<nodeBlocks, 256, 0, stream>>>(x, pos, WT, nb1, nb2, lW1, lb1, u, v);

    for (int l = 0; l < 3; ++l) {
        kAgg<<<aggBlocks, 256, 0, stream>>>(rowPtr, srcList, u, v, aggH);
        if (l < 2) {
            kB<<<nodeBlocks, 256, 0, stream>>>(
                aggH, pos, rowPtr, WT, l,
                lb2 + l * 64, gb1 + l * 64, gb2 + l * 64,
                lW1 + (size_t)(l + 1) * 131 * 64, lb1 + (l + 1) * 64,
                u, v);
        } else {
            kC<<<nodeBlocks, 256, 0, stream>>>(
                aggH, rowPtr, batch, WT,
                lb2 + l * 64, gb1 + l * 64, gb2 + l * 64,
                lin1b, lin2b, out);
        }
    }
}

// Round 9
// 303.306 us; speedup vs baseline: 4.3477x; 1.0061x over previous
//
#include <hip/hip_runtime.h>

#define N_NODES 50000
#define N_EDGES 800000
#define NGRAPH  128
#define XPITCH  72   // ushort pitch: 72*2=144B, 16B-aligned rows, 2-way (free) banks
#define NB      391  // dst buckets of 128 nodes
#define HEPB    4096
#define SEPB    8192

typedef short bf16x8 __attribute__((ext_vector_type(8)));
typedef float f32x4  __attribute__((ext_vector_type(4)));

// ---------------------------------------------------------------------------
// helpers
// ---------------------------------------------------------------------------

__device__ __forceinline__ float atomAddF(float* p, float v) {
#if defined(__gfx950__) || defined(__AMDGCN__)
    return unsafeAtomicAdd(p, v);
#else
    return atomicAdd(p, v);
#endif
}

__device__ __forceinline__ unsigned short f2bf(float x) {  // RNE f32 -> bf16
    unsigned u = __builtin_bit_cast(unsigned, x);
    u += 0x7fffu + ((u >> 16) & 1u);
    return (unsigned short)(u >> 16);
}
__device__ __forceinline__ float bf2f(unsigned short h) {
    return __builtin_bit_cast(float, (unsigned)h << 16);
}

__device__ __forceinline__ f32x4 mk4(float b) { f32x4 a = {b, b, b, b}; return a; }

// One 16x16 tile vs weight mat, A-frags preloaded in regs.
template<int NKC, int KROW>
__device__ __forceinline__ f32x4 w_tile(const bf16x8* a,
                                        const unsigned short* __restrict__ Wm,
                                        int nt, int col, int quad, f32x4 acc) {
    const unsigned short* wp = Wm + (nt * 16 + col) * KROW + quad * 8;
#pragma unroll
    for (int c = 0; c < NKC; ++c) {
        bf16x8 b = *(const bf16x8*)(wp + c * 32);
        acc = __builtin_amdgcn_mfma_f32_16x16x32_bf16(a[c], b, acc, 0, 0, 0);
    }
    return acc;
}

// load A-frags (wave-private slice, rows = local m, m=col)
template<int NKC>
__device__ __forceinline__ void a_load(const unsigned short* __restrict__ sl,
                                       int col, int quad, bf16x8* a) {
    a[0] = *(const bf16x8*)(sl + col * XPITCH + quad * 8);
    if (NKC > 1) a[1] = *(const bf16x8*)(sl + col * XPITCH + quad * 8 + 32);
}

// write NNT n-tiles back into wave slice (in place; all A reads already done)
template<int NNT>
__device__ __forceinline__ void w_store(unsigned short* __restrict__ sl,
                                        int col, int quad, const f32x4* acc4,
                                        bool relu) {
#pragma unroll
    for (int nt = 0; nt < NNT; ++nt)
#pragma unroll
        for (int r = 0; r < 4; ++r) {
            float x = acc4[nt][r];
            if (relu) x = fmaxf(x, 0.f);
            sl[(quad * 4 + r) * XPITCH + nt * 16 + col] = f2bf(x);
        }
}

// store 4 n-tiles to global rows (node-major bf16[64])
__device__ __forceinline__ void g_store(unsigned short* __restrict__ g, int gn0,
                                        int col, int quad, const f32x4* acc4) {
#pragma unroll
    for (int nt = 0; nt < 4; ++nt)
#pragma unroll
        for (int r = 0; r < 4; ++r) {
            int node = gn0 + quad * 4 + r;
            if (node < N_NODES)
                g[(size_t)node * 64 + nt * 16 + col] = f2bf(acc4[nt][r]);
        }
}

// ---------------------------------------------------------------------------
// weight prep (transpose + bf16 into B-operand layout); also zeroes gHist/out
// ---------------------------------------------------------------------------
#define OFF_NW1T  0
#define OFF_NW2T  2048
#define OFF_LYR   6144
#define LYR_SZ    20480
#define OFF_LIN1T 67584
#define OFF_LIN2T 69632
#define WT_TOTAL  70144

__global__ __launch_bounds__(256) void kPrep(
    const float* __restrict__ nW1, const float* __restrict__ nW2,
    const float* __restrict__ lW1, const float* __restrict__ lW2,
    const float* __restrict__ gW1, const float* __restrict__ gW2,
    const float* __restrict__ lin1W, const float* __restrict__ lin2W,
    unsigned short* __restrict__ WT, int* __restrict__ gHist,
    float* __restrict__ out) {
    int i = blockIdx.x * 256 + threadIdx.x;
    if (blockIdx.x == 0) {
        for (int k = threadIdx.x; k < NB; k += 256) gHist[k] = 0;
        for (int k = threadIdx.x; k < NGRAPH * 8; k += 256) out[k] = 0.f;
    }
    if (i >= WT_TOTAL) return;
    int j = i;
    if (j < 2048) {
        int n = j >> 5, k = j & 31;
        WT[i] = (k < 16) ? f2bf(nW1[k * 64 + n]) : 0;
        return;
    }
    j -= 2048;
    if (j < 4096) {
        int n = j >> 6, k = j & 63;
        WT[i] = f2bf(nW2[k * 64 + n]);
        return;
    }
    j -= 4096;
    if (j < 3 * LYR_SZ) {
        int l = j / LYR_SZ;  j -= l * LYR_SZ;
        int m = j >> 12;     j &= 4095;
        int n = j >> 6, k = j & 63;
        const float* src;
        if (m == 0)      src = lW1 + (size_t)l * 131 * 64;
        else if (m == 1) src = lW1 + (size_t)l * 131 * 64 + 64 * 64;
        else if (m == 2) src = lW2 + (size_t)l * 4096;
        else if (m == 3) src = gW1 + (size_t)l * 4096;
        else             src = gW2 + (size_t)l * 4096;
        WT[i] = f2bf(src[k * 64 + n]);
        return;
    }
    j -= 3 * LYR_SZ;
    if (j < 2048) {
        int n = j >> 6, k = j & 63;
        WT[i] = f2bf(lin1W[k * 32 + n]);
        return;
    }
    j -= 2048;
    {
        int n = j >> 5, k = j & 31;
        WT[i] = (n < 8) ? f2bf(lin2W[k * 8 + n]) : 0;
    }
}

// ---------------------------------------------------------------------------
// bucket build: hist -> scan -> bucket scatter -> per-bucket counting sort
// ---------------------------------------------------------------------------
__global__ __launch_bounds__(256) void kHist(const int* __restrict__ ei,
                                             int* __restrict__ gHist) {
    __shared__ int h[NB];
    int tid = threadIdx.x;
    for (int i = tid; i < NB; i += 256) h[i] = 0;
    __syncthreads();
    int base = blockIdx.x * HEPB;
#pragma unroll
    for (int k = 0; k < HEPB; k += 256) {
        int e = base + k + tid;
        if (e < N_EDGES) atomicAdd(&h[ei[N_EDGES + e] >> 7], 1);
    }
    __syncthreads();
    for (int i = tid; i < NB; i += 256)
        if (h[i]) atomicAdd(&gHist[i], h[i]);
}

__global__ __launch_bounds__(256) void kScanB(const int* __restrict__ gHist,
                                              int* __restrict__ bucketOff,
                                              int* __restrict__ cursor) {
    __shared__ int s0[512], s1[512];
    int tid = threadIdx.x;
    for (int e = tid; e < 512; e += 256) s0[e] = (e < NB) ? gHist[e] : 0;
    __syncthreads();
    int* sp = s0; int* dp = s1;
    for (int off = 1; off < 512; off <<= 1) {
        for (int e = tid; e < 512; e += 256)
            dp[e] = sp[e] + ((e >= off) ? sp[e - off] : 0);
        __syncthreads();
        int* t = sp; sp = dp; dp = t;
    }
    for (int e = tid; e < NB; e += 256) {
        int excl = sp[e] - gHist[e];
        bucketOff[e] = excl;
        cursor[e] = excl;
    }
    if (tid == 0) bucketOff[NB] = sp[NB - 1];
}

__global__ __launch_bounds__(256) void kScat(const int* __restrict__ ei,
                                             int* __restrict__ cursor,
                                             int* __restrict__ packs) {
    __shared__ int sdata[SEPB];
    __shared__ int hist[NB];
    __shared__ int loff[NB + 1];
    __shared__ int gbase[NB];
    __shared__ int sc0[512], sc1[512];
    int tid = threadIdx.x;
    int base = blockIdx.x * SEPB;
    int nE = min(SEPB, N_EDGES - base);

    for (int i = tid; i < NB; i += 256) hist[i] = 0;
    __syncthreads();

    int myPack[SEPB / 256];
    unsigned short myRank[SEPB / 256];
#pragma unroll
    for (int kk = 0; kk < SEPB / 256; ++kk) {
        int e = base + kk * 256 + tid;
        if (e < N_EDGES) {
            int s = ei[e], d = ei[N_EDGES + e];
            myPack[kk] = (s << 16) | d;
            myRank[kk] = (unsigned short)atomicAdd(&hist[d >> 7], 1);
        }
    }
    __syncthreads();

    for (int e = tid; e < 512; e += 256) sc0[e] = (e < NB) ? hist[e] : 0;
    __syncthreads();
    int* sp = sc0; int* dp = sc1;
    for (int off = 1; off < 512; off <<= 1) {
        for (int e = tid; e < 512; e += 256)
            dp[e] = sp[e] + ((e >= off) ? sp[e - off] : 0);
        __syncthreads();
        int* t = sp; sp = dp; dp = t;
    }
    for (int e = tid; e < NB; e += 256) loff[e] = sp[e] - hist[e];
    if (tid == 0) loff[NB] = sp[NB - 1];
    __syncthreads();

    for (int e = tid; e < NB; e += 256)
        gbase[e] = hist[e] ? atomicAdd(&cursor[e], hist[e]) : 0;
#pragma unroll
    for (int kk = 0; kk < SEPB / 256; ++kk) {
        int e = base + kk * 256 + tid;
        if (e < N_EDGES) {
            int p = myPack[kk];
            int b = (p & 0xffff) >> 7;
            sdata[loff[b] + myRank[kk]] = p;
        }
    }
    __syncthreads();

    for (int i = tid; i < nE; i += 256) {
        int p = sdata[i];
        int b = (p & 0xffff) >> 7;
        packs[gbase[b] + (i - loff[b])] = p;
    }
}

__global__ __launch_bounds__(256) void kSort(
    const int* __restrict__ bucketOff, const int* __restrict__ packs,
    unsigned short* __restrict__ srcList, int* __restrict__ rowPtr) {
    __shared__ int hist[128];
    __shared__ int cur[128];
    __shared__ int sc0[128], sc1[128];
    int tid = threadIdx.x;
    int nbk = blockIdx.x;
    int nodeBase = nbk * 128;
    int nvalid = min(128, N_NODES - nodeBase);
    int eb = bucketOff[nbk], ee = bucketOff[nbk + 1];

    if (tid < 128) hist[tid] = 0;
    __syncthreads();
    for (int i = eb + tid; i < ee; i += 256)
        atomicAdd(&hist[packs[i] & 127], 1);
    __syncthreads();

    if (tid < 128) sc0[tid] = hist[tid];
    __syncthreads();
    int* sp = sc0; int* dp = sc1;
    for (int off = 1; off < 128; off <<= 1) {
        if (tid < 128) dp[tid] = sp[tid] + ((tid >= off) ? sp[tid - off] : 0);
        __syncthreads();
        int* t = sp; sp = dp; dp = t;
    }
    if (tid < 128) {
        int excl = eb + sp[tid] - hist[tid];
        if (tid < nvalid) rowPtr[nodeBase + tid] = excl;
        cur[tid] = excl;
    }
    if (nbk == NB - 1 && tid == 0) rowPtr[N_NODES] = ee;
    __syncthreads();

    for (int i = eb + tid; i < ee; i += 256) {
        int p = packs[i];
        int pos = atomicAdd(&cur[p & 127], 1);
        srcList[pos] = (unsigned short)(((unsigned)p) >> 16);
    }
}

// ---------------------------------------------------------------------------
// aggregation: wave/node, 16 lanes/edge; quarter q owns edges b+4q..b+4q+3
// (stride 16) -> 4 independent ushort4 row-gathers in flight per quarter,
// 16 per wave. Tail (<16 edges) via stride-4 loop. shfl_xor(16|32) reduce.
// aggH may alias u (u row read before any write; wave owns row n).
// ---------------------------------------------------------------------------
__global__ __launch_bounds__(256) void kAgg(const int* __restrict__ rowPtr,
                                            const unsigned short* __restrict__ srcList,
                                            const unsigned short* __restrict__ u,
                                            const unsigned short* __restrict__ v,
                                            unsigned short* __restrict__ aggH) {
    int gt = blockIdx.x * 256 + threadIdx.x;
    int n = gt >> 6;
    int lane = gt & 63;
    if (n >= N_NODES) return;
    int sub = lane & 15;
    int q = lane >> 4;

    ushort4 uu = *(const ushort4*)(u + (size_t)n * 64 + sub * 4);
    float u0 = bf2f(uu.x), u1 = bf2f(uu.y), u2 = bf2f(uu.z), u3 = bf2f(uu.w);

    int b = rowPtr[n], e = rowPtr[n + 1];
    int deg = e - b;
    int full16 = deg & ~15;
    float a0 = 0.f, a1 = 0.f, a2 = 0.f, a3 = 0.f;

    // main: 16 edges per wave-iteration, 4 per quarter
    for (int g0 = 0; g0 < full16; g0 += 16) {
        int i = b + g0 + 4 * q;
        int s0 = srcList[i];
        int s1 = srcList[i + 1];
        int s2 = srcList[i + 2];
        int s3 = srcList[i + 3];
        ushort4 w0 = *(const ushort4*)(v + (size_t)s0 * 64 + sub * 4);
        ushort4 w1 = *(const ushort4*)(v + (size_t)s1 * 64 + sub * 4);
        ushort4 w2 = *(const ushort4*)(v + (size_t)s2 * 64 + sub * 4);
        ushort4 w3 = *(const ushort4*)(v + (size_t)s3 * 64 + sub * 4);
        a0 += fmaxf(u0 + bf2f(w0.x), 0.f) + fmaxf(u0 + bf2f(w1.x), 0.f)
            + fmaxf(u0 + bf2f(w2.x), 0.f) + fmaxf(u0 + bf2f(w3.x), 0.f);
        a1 += fmaxf(u1 + bf2f(w0.y), 0.f) + fmaxf(u1 + bf2f(w1.y), 0.f)
            + fmaxf(u1 + bf2f(w2.y), 0.f) + fmaxf(u1 + bf2f(w3.y), 0.f);
        a2 += fmaxf(u2 + bf2f(w0.z), 0.f) + fmaxf(u2 + bf2f(w1.z), 0.f)
            + fmaxf(u2 + bf2f(w2.z), 0.f) + fmaxf(u2 + bf2f(w3.z), 0.f);
        a3 += fmaxf(u3 + bf2f(w0.w), 0.f) + fmaxf(u3 + bf2f(w1.w), 0.f)
            + fmaxf(u3 + bf2f(w2.w), 0.f) + fmaxf(u3 + bf2f(w3.w), 0.f);
    }
    // tail: up to 15 edges, 1 per quarter per iter
    for (int i = b + full16 + q; i < e; i += 4) {
        int s0 = srcList[i];
        ushort4 w0 = *(const ushort4*)(v + (size_t)s0 * 64 + sub * 4);
        a0 += fmaxf(u0 + bf2f(w0.x), 0.f);
        a1 += fmaxf(u1 + bf2f(w0.y), 0.f);
        a2 += fmaxf(u2 + bf2f(w0.z), 0.f);
        a3 += fmaxf(u3 + bf2f(w0.w), 0.f);
    }

    a0 += __shfl_xor(a0, 16); a0 += __shfl_xor(a0, 32);
    a1 += __shfl_xor(a1, 16); a1 += __shfl_xor(a1, 32);
    a2 += __shfl_xor(a2, 16); a2 += __shfl_xor(a2, 32);
    a3 += __shfl_xor(a3, 16); a3 += __shfl_xor(a3, 32);

    if (q == 0) {
        ushort4 o;
        o.x = f2bf(a0); o.y = f2bf(a1); o.z = f2bf(a2); o.w = f2bf(a3);
        *(ushort4*)(aggH + (size_t)n * 64 + sub * 4) = o;
    }
}

// ---------------------------------------------------------------------------
// kA: barrier-free wave pipelines (16 nodes/wave, private LDS slice)
// ---------------------------------------------------------------------------
__global__ __launch_bounds__(256) void kA(
    const float* __restrict__ x, const float* __restrict__ pos,
    const unsigned short* __restrict__ WT,
    const float* __restrict__ nb1, const float* __restrict__ nb2,
    const float* __restrict__ lW1f, const float* __restrict__ lb1,
    unsigned short* __restrict__ u, unsigned short* __restrict__ v) {
    __shared__ unsigned short SL[4 * 16 * XPITCH];
    __shared__ float posW[4 * 48];
    int tid = threadIdx.x;
    int lane = tid & 63;
    int wv = __builtin_amdgcn_readfirstlane(tid >> 6);
    unsigned short* sl = SL + wv * 16 * XPITCH;
    float* pw = posW + wv * 48;
    int gn0 = blockIdx.x * 64 + wv * 16;
    int col = lane & 15, quad = lane >> 4;

    for (int idx = lane; idx < 512; idx += 64) {
        int m = idx >> 5, k = idx & 31;
        int node = gn0 + m;
        float val = (k < 16 && node < N_NODES) ? x[(size_t)node * 16 + k] : 0.f;
        sl[m * XPITCH + k] = f2bf(val);
    }
    for (int idx = lane; idx < 48; idx += 64) {
        int node = gn0 + idx / 3;
        pw[idx] = (node < N_NODES) ? pos[(size_t)node * 3 + idx % 3] : 0.f;
    }

    bf16x8 a[2];
    f32x4 acc4[4];

    a_load<1>(sl, col, quad, a);
#pragma unroll
    for (int nt = 0; nt < 4; ++nt)
        acc4[nt] = w_tile<1, 32>(a, WT + OFF_NW1T, nt, col, quad, mk4(nb1[nt * 16 + col]));
    w_store<4>(sl, col, quad, acc4, true);

    a_load<2>(sl, col, quad, a);
#pragma unroll
    for (int nt = 0; nt < 4; ++nt)
        acc4[nt] = w_tile<2, 64>(a, WT + OFF_NW2T, nt, col, quad, mk4(nb2[nt * 16 + col]));
    w_store<4>(sl, col, quad, acc4, false);

    const unsigned short* aT = WT + OFF_LYR;
    const unsigned short* bT = aT + 4096;
    const float* W1c = lW1f + 128 * 64;

    a_load<2>(sl, col, quad, a);
#pragma unroll
    for (int nt = 0; nt < 4; ++nt)
        acc4[nt] = w_tile<2, 64>(a, aT, nt, col, quad, mk4(0.f));
    g_store(u, gn0, col, quad, acc4);

    float px[4], py[4], pz[4];
#pragma unroll
    for (int r = 0; r < 4; ++r) {
        px[r] = pw[(quad * 4 + r) * 3 + 0];
        py[r] = pw[(quad * 4 + r) * 3 + 1];
        pz[r] = pw[(quad * 4 + r) * 3 + 2];
    }
#pragma unroll
    for (int nt = 0; nt < 4; ++nt) {
        int ch = nt * 16 + col;
        acc4[nt] = w_tile<2, 64>(a, bT, nt, col, quad, mk4(lb1[ch]));
        float w0 = W1c[ch], w1 = W1c[64 + ch], w2 = W1c[128 + ch];
#pragma unroll
        for (int r = 0; r < 4; ++r)
            acc4[nt][r] += px[r] * w0 + py[r] * w1 + pz[r] * w2;
    }
    g_store(v, gn0, col, quad, acc4);
}

// ---------------------------------------------------------------------------
// kB (layers 0,1): barrier-free wave pipelines
// ---------------------------------------------------------------------------
__global__ __launch_bounds__(256) void kB(
    const unsigned short* __restrict__ aggH, const float* __restrict__ pos,
    const int* __restrict__ rowPtr, const unsigned short* __restrict__ WT,
    int l,
    const float* __restrict__ lb2, const float* __restrict__ gb1,
    const float* __restrict__ gb2,
    const float* __restrict__ lW1f_next, const float* __restrict__ b1n,
    unsigned short* __restrict__ u, unsigned short* __restrict__ v) {
    __shared__ unsigned short SL[4 * 16 * XPITCH];
    __shared__ float posW[4 * 48];
    __shared__ float degW[4 * 16];
    int tid = threadIdx.x;
    int lane = tid & 63;
    int wv = __builtin_amdgcn_readfirstlane(tid >> 6);
    unsigned short* sl = SL + wv * 16 * XPITCH;
    float* pw = posW + wv * 48;
    float* dw = degW + wv * 16;
    int gn0 = blockIdx.x * 64 + wv * 16;
    int col = lane & 15, quad = lane >> 4;

    const unsigned short* LYR = WT + OFF_LYR + (size_t)l * LYR_SZ;
    const unsigned short* lW2T = LYR + 2 * 4096;
    const unsigned short* gW1T = LYR + 3 * 4096;
    const unsigned short* gW2T = LYR + 4 * 4096;
    const unsigned short* aTn = WT + OFF_LYR + (size_t)(l + 1) * LYR_SZ;
    const unsigned short* bTn = aTn + 4096;

    const uint4* ag = (const uint4*)(aggH + (size_t)gn0 * 64);
    for (int idx = lane; idx < 128; idx += 64) {
        int m = idx >> 3, seg = idx & 7;
        uint4 d = (gn0 + m < N_NODES) ? ag[idx] : make_uint4(0u, 0u, 0u, 0u);
        *(uint4*)&sl[m * XPITCH + seg * 8] = d;
    }
    for (int idx = lane; idx < 48; idx += 64) {
        int node = gn0 + idx / 3;
        pw[idx] = (node < N_NODES) ? pos[(size_t)node * 3 + idx % 3] : 0.f;
    }
    if (lane < 16) {
        int node = min(gn0 + lane, N_NODES - 1);
        dw[lane] = (float)(rowPtr[node + 1] - rowPtr[node]);
    }

    bf16x8 a[2];
    f32x4 acc4[4];
    float dgr[4];
#pragma unroll
    for (int r = 0; r < 4; ++r) dgr[r] = dw[quad * 4 + r];

    a_load<2>(sl, col, quad, a);
#pragma unroll
    for (int nt = 0; nt < 4; ++nt) {
        float b = lb2[nt * 16 + col];
        f32x4 init = {dgr[0] * b, dgr[1] * b, dgr[2] * b, dgr[3] * b};
        acc4[nt] = w_tile<2, 64>(a, lW2T, nt, col, quad, init);
    }
    w_store<4>(sl, col, quad, acc4, false);

    a_load<2>(sl, col, quad, a);
#pragma unroll
    for (int nt = 0; nt < 4; ++nt)
        acc4[nt] = w_tile<2, 64>(a, gW1T, nt, col, quad, mk4(gb1[nt * 16 + col]));
    w_store<4>(sl, col, quad, acc4, true);

    a_load<2>(sl, col, quad, a);
#pragma unroll
    for (int nt = 0; nt < 4; ++nt)
        acc4[nt] = w_tile<2, 64>(a, gW2T, nt, col, quad, mk4(gb2[nt * 16 + col]));
    w_store<4>(sl, col, quad, acc4, true);

    a_load<2>(sl, col, quad, a);
#pragma unroll
    for (int nt = 0; nt < 4; ++nt)
        acc4[nt] = w_tile<2, 64>(a, aTn, nt, col, quad, mk4(0.f));
    g_store(u, gn0, col, quad, acc4);

    const float* W1c = lW1f_next + 128 * 64;
    float px[4], py[4], pz[4];
#pragma unroll
    for (int r = 0; r < 4; ++r) {
        px[r] = pw[(quad * 4 + r) * 3 + 0];
        py[r] = pw[(quad * 4 + r) * 3 + 1];
        pz[r] = pw[(quad * 4 + r) * 3 + 2];
    }
#pragma unroll
    for (int nt = 0; nt < 4; ++nt) {
        int ch = nt * 16 + col;
        acc4[nt] = w_tile<2, 64>(a, bTn, nt, col, quad, mk4(b1n[ch]));
        float w0 = W1c[ch], w1 = W1c[64 + ch], w2 = W1c[128 + ch];
#pragma unroll
        for (int r = 0; r < 4; ++r)
            acc4[nt][r] += px[r] * w0 + py[r] * w1 + pz[r] * w2;
    }
    g_store(v, gn0, col, quad, acc4);
}

// ---------------------------------------------------------------------------
// kC (layer 2): wave pipelines + block-shared readout bins (2 barriers total)
// ---------------------------------------------------------------------------
__global__ __launch_bounds__(256) void kC(
    const unsigned short* __restrict__ aggH, const int* __restrict__ rowPtr,
    const int* __restrict__ batch, const unsigned short* __restrict__ WT,
    const float* __restrict__ lb2, const float* __restrict__ gb1,
    const float* __restrict__ gb2,
    const float* __restrict__ lin1b, const float* __restrict__ lin2b,
    float* __restrict__ out) {
    __shared__ unsigned short SL[4 * 16 * XPITCH];
    __shared__ float degW[4 * 16];
    __shared__ int batchW[64];
    __shared__ float bins[128 * 8];
    int tid = threadIdx.x;
    int lane = tid & 63;
    int wv = __builtin_amdgcn_readfirstlane(tid >> 6);
    unsigned short* sl = SL + wv * 16 * XPITCH;
    float* dw = degW + wv * 16;
    int nodeBase = blockIdx.x * 64;
    int gn0 = nodeBase + wv * 16;
    int nvalid = min(64, N_NODES - nodeBase);
    int col = lane & 15, quad = lane >> 4;

    const unsigned short* LYR = WT + OFF_LYR + 2 * LYR_SZ;
    const unsigned short* lW2T = LYR + 2 * 4096;
    const unsigned short* gW1T = LYR + 3 * 4096;
    const unsigned short* gW2T = LYR + 4 * 4096;
    const unsigned short* lin1T = WT + OFF_LIN1T;
    const unsigned short* lin2T = WT + OFF_LIN2T;

    for (int idx = tid; idx < 128 * 8; idx += 256) bins[idx] = 0.f;
    const uint4* ag = (const uint4*)(aggH + (size_t)gn0 * 64);
    for (int idx = lane; idx < 128; idx += 64) {
        int m = idx >> 3, seg = idx & 7;
        uint4 d = (gn0 + m < N_NODES) ? ag[idx] : make_uint4(0u, 0u, 0u, 0u);
        *(uint4*)&sl[m * XPITCH + seg * 8] = d;
    }
    if (lane < 16) {
        int node = min(gn0 + lane, N_NODES - 1);
        dw[lane] = (float)(rowPtr[node + 1] - rowPtr[node]);
        batchW[wv * 16 + lane] = batch[node];
    }
    __syncthreads();   // bins zero + batchW visible before any atomic add

    bf16x8 a[2];
    f32x4 acc4[4];
    float dgr[4];
#pragma unroll
    for (int r = 0; r < 4; ++r) dgr[r] = dw[quad * 4 + r];

    a_load<2>(sl, col, quad, a);
#pragma unroll
    for (int nt = 0; nt < 4; ++nt) {
        float b = lb2[nt * 16 + col];
        f32x4 init = {dgr[0] * b, dgr[1] * b, dgr[2] * b, dgr[3] * b};
        acc4[nt] = w_tile<2, 64>(a, lW2T, nt, col, quad, init);
    }
    w_store<4>(sl, col, quad, acc4, false);

    a_load<2>(sl, col, quad, a);
#pragma unroll
    for (int nt = 0; nt < 4; ++nt)
        acc4[nt] = w_tile<2, 64>(a, gW1T, nt, col, quad, mk4(gb1[nt * 16 + col]));
    w_store<4>(sl, col, quad, acc4, true);

    a_load<2>(sl, col, quad, a);
#pragma unroll
    for (int nt = 0; nt < 4; ++nt)
        acc4[nt] = w_tile<2, 64>(a, gW2T, nt, col, quad, mk4(gb2[nt * 16 + col]));
    w_store<4>(sl, col, quad, acc4, true);

    a_load<2>(sl, col, quad, a);
#pragma unroll
    for (int nt = 0; nt < 2; ++nt)
        acc4[nt] = w_tile<2, 64>(a, lin1T, nt, col, quad, mk4(lin1b[nt * 16 + col]));
    w_store<2>(sl, col, quad, acc4, true);

    a_load<1>(sl, col, quad, a);
    f32x4 o = w_tile<1, 32>(a, lin2T, 0, col, quad,
                            mk4(col < 8 ? lin2b[col] : 0.f));

    int gmin = batch[nodeBase];
    if (col < 8) {
#pragma unroll
        for (int r = 0; r < 4; ++r) {
            int nl = wv * 16 + quad * 4 + r;
            if (nl < nvalid)
                atomicAdd(&bins[(batchW[nl] - gmin) * 8 + col], o[r]);
        }
    }
    __syncthreads();
    int gmax = batch[nodeBase + nvalid - 1];
    int nb8 = (gmax - gmin + 1) * 8;
    for (int idx = tid; idx < nb8; idx += 256)
        atomAddF(&out[gmin * 8 + idx], bins[idx]);
}

// ---------------------------------------------------------------------------
// launch
// ---------------------------------------------------------------------------
extern "C" void kernel_launch(void* const* d_in, const int* in_sizes, int n_in,
                              void* d_out, int out_size, void* d_ws, size_t ws_size,
                              hipStream_t stream) {
    const float* x     = (const float*)d_in[0];
    const float* pos   = (const float*)d_in[1];
    const int*   ei    = (const int*)d_in[2];
    const int*   batch = (const int*)d_in[3];
    const float* nW1   = (const float*)d_in[4];
    const float* nb1   = (const float*)d_in[5];
    const float* nW2   = (const float*)d_in[6];
    const float* nb2   = (const float*)d_in[7];
    const float* lW1   = (const float*)d_in[8];
    const float* lb1   = (const float*)d_in[9];
    const float* lW2   = (const float*)d_in[10];
    const float* lb2   = (const float*)d_in[11];
    const float* gW1   = (const float*)d_in[12];
    const float* gb1   = (const float*)d_in[13];
    const float* gW2   = (const float*)d_in[14];
    const float* gb2   = (const float*)d_in[15];
    const float* lin1W = (const float*)d_in[16];
    const float* lin1b = (const float*)d_in[17];
    const float* lin2W = (const float*)d_in[18];
    const float* lin2b = (const float*)d_in[19];
    float* out = (float*)d_out;

    // workspace (u doubles as aggH)
    unsigned short* u  = (unsigned short*)d_ws;          // N*64 bf16
    unsigned short* v  = u + (size_t)N_NODES * 64;       // N*64 bf16
    unsigned short* WT = v + (size_t)N_NODES * 64;       // WT_TOTAL bf16
    int* gHist = (int*)(WT + WT_TOTAL);                  // NB
    int* bucketOff = gHist + NB;                         // NB+1
    int* cursor = bucketOff + NB + 1;                    // NB
    int* rowPtr = cursor + NB;                           // N+1
    int* packs = rowPtr + N_NODES + 1;                   // E int
    unsigned short* srcList = (unsigned short*)(packs + N_EDGES); // E ushort
    unsigned short* aggH = u;

    const int nodeBlocks = (N_NODES + 63) / 64;
    const int aggBlocks  = (N_NODES * 64 + 255) / 256;

    kPrep<<<(WT_TOTAL + 255) / 256, 256, 0, stream>>>(nW1, nW2, lW1, lW2, gW1, gW2,
                                                      lin1W, lin2W, WT, gHist, out);
    kHist<<<(N_EDGES + HEPB - 1) / HEPB, 256, 0, stream>>>(ei, gHist);
    kScanB<<<1, 256, 0, stream>>>(gHist, bucketOff, cursor);
    kScat<<<(N_EDGES + SEPB - 1) / SEPB, 256, 0, stream>>>(ei, cursor, packs);
    kSort<<<NB, 256, 0, stream>>>(bucketOff, packs, srcList, rowPtr);

    kA<<<nodeBlocks, 256, 0, stream>>>(x, pos, WT, nb1, nb2, lW1, lb1, u, v);

    for (int l = 0; l < 3; ++l) {
        kAgg<<<aggBlocks, 256, 0, stream>>>(rowPtr, srcList, u, v, aggH);
        if (l < 2) {
            kB<<<nodeBlocks, 256, 0, stream>>>(
                aggH, pos, rowPtr, WT, l,
                lb2 + l * 64, gb1 + l * 64, gb2 + l * 64,
                lW1 + (size_t)(l + 1) * 131 * 64, lb1 + (l + 1) * 64,
                u, v);
        } else {
            kC<<<nodeBlocks, 256, 0, stream>>>(
                aggH, rowPtr, batch, WT,
                lb2 + l * 64, gb1 + l * 64, gb2 + l * 64,
                lin1b, lin2b, out);
        }
    }
}